// Round 5
// baseline (556.612 us; speedup 1.0000x reference)
//
#include <hip/hip_runtime.h>
#include <hip/hip_bf16.h>
#include <math.h>

// ---- problem constants ----
#define DM    1024      // d_model
#define DIP   4384      // d_in_proj
#define NP1   4480      // padded in_proj rows
#define NPX   4352      // z + xBC columns (combined main GEMM width)
#define DI    2048      // d_inner
#define CD    2304      // conv dim
#define NH    32        // heads
#define HD    64        // head dim
#define DS    128       // d_state
#define CH    256       // chunk
#define NCH   16        // chunks per sequence
#define BSZ   2
#define SEQ   4096
#define NTOK  (BSZ*SEQ) // 8192

typedef __bf16 bf16_t;
typedef __attribute__((ext_vector_type(8))) __bf16 bf16x8;
typedef __attribute__((ext_vector_type(4))) float f32x4;

__device__ __forceinline__ f32x4 mfma16(bf16x8 a, bf16x8 b, f32x4 c) {
    return __builtin_amdgcn_mfma_f32_16x16x32_bf16(a, b, c, 0, 0, 0);
}

__device__ __forceinline__ void gload_lds16(const bf16_t* g, bf16_t* l) {
    __builtin_amdgcn_global_load_lds(
        (const __attribute__((address_space(1))) unsigned int*)g,
        (__attribute__((address_space(3))) unsigned int*)l, 16, 0, 0);
}

// ---------------- fused converts ----------------
#define CVT_U   (NTOK * DM)
#define CVT_WI  (NP1 * DM)
#define CVT_WO  (DM * DI)
__global__ void k_cvt_all(const float* __restrict__ u, const float* __restrict__ wi,
                          const float* __restrict__ wo,
                          bf16_t* __restrict__ u_bf, bf16_t* __restrict__ wi_bf,
                          bf16_t* __restrict__ wo_bf) {
    int i = blockIdx.x * 256 + threadIdx.x;
    if (i < CVT_U) {
        u_bf[i] = (bf16_t)u[i];
    } else if (i < CVT_U + CVT_WI) {
        int j = i - CVT_U;
        int r = j >> 10;  // DM=1024
        wi_bf[j] = (r < DIP) ? (bf16_t)wi[j] : (bf16_t)0.f;
    } else if (i < CVT_U + CVT_WI + CVT_WO) {
        int j = i - CVT_U - CVT_WI;
        wo_bf[j] = (bf16_t)wo[j];
    }
}

// ---------------- GEMM 128x128 (m97-style + XOR swizzle) ----------------
template <typename OutT>
__global__ __launch_bounds__(256) void k_gemm(const bf16_t* __restrict__ A,
                                              const bf16_t* __restrict__ Bt,
                                              OutT* __restrict__ C, int K, int ldc) {
    __shared__ __align__(16) bf16_t sA[128 * 32];
    __shared__ __align__(16) bf16_t sB[128 * 32];
    int tid = threadIdx.x, wave = tid >> 6, lane = tid & 63;
    int l15 = lane & 15, quad = lane >> 4;
    int m0 = blockIdx.y * 128, n0 = blockIdx.x * 128;
    int wm = (wave & 1) * 64, wn = (wave >> 1) * 64;
    f32x4 acc[4][4];
#pragma unroll
    for (int i = 0; i < 4; i++)
#pragma unroll
        for (int j = 0; j < 4; j++) acc[i][j] = (f32x4){0.f, 0.f, 0.f, 0.f};

    int srow = lane >> 2, sc = lane & 3;
    int scol = (sc ^ ((srow >> 1) & 3)) * 8;
    const bf16_t* Ag0 = A + (size_t)(m0 + wave * 32 + srow) * K + scol;
    const bf16_t* Ag1 = Ag0 + (size_t)16 * K;
    const bf16_t* Bg0 = Bt + (size_t)(n0 + wave * 32 + srow) * K + scol;
    const bf16_t* Bg1 = Bg0 + (size_t)16 * K;
    bf16_t* lA0 = sA + (wave * 32) * 32;
    bf16_t* lA1 = sA + (wave * 32 + 16) * 32;
    bf16_t* lB0 = sB + (wave * 32) * 32;
    bf16_t* lB1 = sB + (wave * 32 + 16) * 32;
    int rchunk = (quad ^ ((l15 >> 1) & 3)) * 8;

    for (int k0 = 0; k0 < K; k0 += 32) {
        gload_lds16(Ag0 + k0, lA0);
        gload_lds16(Ag1 + k0, lA1);
        gload_lds16(Bg0 + k0, lB0);
        gload_lds16(Bg1 + k0, lB1);
        __syncthreads();
        bf16x8 af[4], bg[4];
#pragma unroll
        for (int mt = 0; mt < 4; mt++) af[mt] = *(const bf16x8*)&sA[(wm + mt * 16 + l15) * 32 + rchunk];
#pragma unroll
        for (int nt = 0; nt < 4; nt++) bg[nt] = *(const bf16x8*)&sB[(wn + nt * 16 + l15) * 32 + rchunk];
#pragma unroll
        for (int mt = 0; mt < 4; mt++)
#pragma unroll
            for (int nt = 0; nt < 4; nt++)
                acc[mt][nt] = mfma16(af[mt], bg[nt], acc[mt][nt]);
        __syncthreads();
    }
#pragma unroll
    for (int mt = 0; mt < 4; mt++)
#pragma unroll
        for (int nt = 0; nt < 4; nt++)
#pragma unroll
            for (int r = 0; r < 4; r++)
                C[(size_t)(m0 + wm + mt * 16 + quad * 4 + r) * ldc + n0 + wn + nt * 16 + l15] =
                    (OutT)acc[mt][nt][r];
}

// ---------------- GEMM 256x128 M-tile: 4 waves as 2(m)x2(n), each 128x64 ----------------
// 32 MFMA per wave per K-step vs 6 staging issues -> better MFMA:barrier amortization at K=1024.
__global__ __launch_bounds__(256) void k_gemm256(const bf16_t* __restrict__ A,
                                                 const bf16_t* __restrict__ Bt,
                                                 bf16_t* __restrict__ C, int K, int ldc) {
    __shared__ __align__(16) bf16_t sA[256 * 32];
    __shared__ __align__(16) bf16_t sB[128 * 32];
    int tid = threadIdx.x, wave = tid >> 6, lane = tid & 63;
    int l15 = lane & 15, quad = lane >> 4;
    int m0 = blockIdx.y * 256, n0 = blockIdx.x * 128;
    int wm = (wave & 1) * 128, wn = (wave >> 1) * 64;
    f32x4 acc[8][4];
#pragma unroll
    for (int i = 0; i < 8; i++)
#pragma unroll
        for (int j = 0; j < 4; j++) acc[i][j] = (f32x4){0.f, 0.f, 0.f, 0.f};

    int srow = lane >> 2, sc = lane & 3;
    int scol = (sc ^ ((srow >> 1) & 3)) * 8;
    // A: wave stages rows [wave*64, wave*64+64) in 4 issues of 16 rows
    const bf16_t* AgB = A + (size_t)(m0 + wave * 64 + srow) * K + scol;
    bf16_t* lA = sA + (wave * 64) * 32;
    // B: wave stages rows [wave*32, wave*32+32) in 2 issues
    const bf16_t* BgB = Bt + (size_t)(n0 + wave * 32 + srow) * K + scol;
    bf16_t* lB = sB + (wave * 32) * 32;
    int rchunk = (quad ^ ((l15 >> 1) & 3)) * 8;

    for (int k0 = 0; k0 < K; k0 += 32) {
#pragma unroll
        for (int i = 0; i < 4; i++) gload_lds16(AgB + (size_t)(16 * i) * K + k0, lA + (16 * i) * 32);
#pragma unroll
        for (int i = 0; i < 2; i++) gload_lds16(BgB + (size_t)(16 * i) * K + k0, lB + (16 * i) * 32);
        __syncthreads();
        bf16x8 af[8], bg[4];
#pragma unroll
        for (int mt = 0; mt < 8; mt++) af[mt] = *(const bf16x8*)&sA[(wm + mt * 16 + l15) * 32 + rchunk];
#pragma unroll
        for (int nt = 0; nt < 4; nt++) bg[nt] = *(const bf16x8*)&sB[(wn + nt * 16 + l15) * 32 + rchunk];
#pragma unroll
        for (int mt = 0; mt < 8; mt++)
#pragma unroll
            for (int nt = 0; nt < 4; nt++)
                acc[mt][nt] = mfma16(af[mt], bg[nt], acc[mt][nt]);
        __syncthreads();
    }
#pragma unroll
    for (int mt = 0; mt < 8; mt++)
#pragma unroll
        for (int nt = 0; nt < 4; nt++)
#pragma unroll
            for (int r = 0; r < 4; r++)
                C[(size_t)(m0 + wm + mt * 16 + quad * 4 + r) * ldc + n0 + wn + nt * 16 + l15] =
                    (bf16_t)acc[mt][nt][r];
}

// ---------------- dt + softplus + per-chunk cumsum of dt*A ----------------
__global__ __launch_bounds__(256) void k_dtcum(const float* __restrict__ dtf,
                                               const float* __restrict__ delta_t,
                                               const float* __restrict__ gamma,
                                               const float* __restrict__ dt_bias,
                                               const float* __restrict__ A_log,
                                               float* __restrict__ dtb, float* __restrict__ acum) {
    int blk = blockIdx.x;
    int h = blk & (NH - 1), bc = blk >> 5;
    int q = threadIdx.x;
    size_t tok = (size_t)bc * CH + q;
    float x = dtf[tok * 128 + h] + gamma[h] * delta_t[tok] + dt_bias[h];
    float dt = (x > 20.f) ? x : log1pf(expf(x));
    float Ah = -expf(A_log[h]);
    __shared__ __align__(16) float s[CH];
    s[q] = dt * Ah;
    __syncthreads();
#pragma unroll
    for (int off = 1; off < CH; off <<= 1) {
        float v = (q >= off) ? s[q - off] : 0.f;
        __syncthreads();
        s[q] += v;
        __syncthreads();
    }
    dtb[(size_t)blk * CH + q] = dt;
    acum[(size_t)blk * CH + q] = s[q];
}

// ---------------- causal depthwise conv (4 taps) + bias + silu -> bf16 ----------------
__global__ __launch_bounds__(256) void k_conv(const bf16_t* __restrict__ zxp,
                                              const float* __restrict__ cw,
                                              const float* __restrict__ cb,
                                              bf16_t* __restrict__ xBC) {
    int ch = blockIdx.x * 256 + threadIdx.x;
    int tok0 = blockIdx.y * 8;
    int l0 = tok0 & (SEQ - 1);
    float w0 = cw[ch * 4], w1 = cw[ch * 4 + 1], w2 = cw[ch * 4 + 2], w3 = cw[ch * 4 + 3];
    float bias = cb[ch];
    float h0 = 0.f, h1 = 0.f, h2 = 0.f;
    if (l0 != 0) {
        h0 = (float)zxp[(size_t)(tok0 - 3) * NPX + ch];
        h1 = (float)zxp[(size_t)(tok0 - 2) * NPX + ch];
        h2 = (float)zxp[(size_t)(tok0 - 1) * NPX + ch];
    }
#pragma unroll
    for (int j = 0; j < 8; j++) {
        float cur = (float)zxp[(size_t)(tok0 + j) * NPX + ch];
        float acc = bias + h0 * w0 + h1 * w1 + h2 * w2 + cur * w3;
        float sv = acc / (1.f + expf(-acc));
        xBC[(size_t)(tok0 + j) * CD + ch] = (bf16_t)sv;
        h0 = h1; h1 = h2; h2 = cur;
    }
}

// ---------------- transpose + dt fold ----------------
__global__ __launch_bounds__(256) void k_trans(const bf16_t* __restrict__ xBC,
                                               const float* __restrict__ dtb,
                                               bf16_t* __restrict__ Xt, bf16_t* __restrict__ Btr) {
    int t = blockIdx.x, bc = blockIdx.y, tid = threadIdx.x;
    __shared__ __align__(16) bf16_t tile[CH][72];
    __shared__ __align__(16) float sdt[CH];
    int chbase = (t < 32) ? t * 64 : DI + (t - 32) * 64;
#pragma unroll
    for (int pp = 0; pp < 8; pp++) {
        int q = pp * 32 + (tid >> 3), col = (tid & 7) * 8;
        *(bf16x8*)&tile[q][col] = *(const bf16x8*)(xBC + (size_t)(bc * CH + q) * CD + chbase + col);
    }
    if (t < 32) sdt[tid] = dtb[(size_t)(bc * NH + t) * CH + tid];
    __syncthreads();
    int pl = tid >> 2, qg = tid & 3;
#pragma unroll
    for (int c8 = 0; c8 < 8; c8++) {
        int q0 = qg * 64 + c8 * 8;
        bf16x8 v;
        if (t < 32) {
#pragma unroll
            for (int j = 0; j < 8; j++) v[j] = (bf16_t)((float)tile[q0 + j][pl] * sdt[q0 + j]);
            size_t row = (size_t)(bc * NH + t) * 64 + pl;
            *(bf16x8*)(Xt + row * CH + q0) = v;
        } else {
#pragma unroll
            for (int j = 0; j < 8; j++) v[j] = tile[q0 + j][pl];
            size_t row = (size_t)bc * DS + (t - 32) * 64 + pl;
            *(bf16x8*)(Btr + row * CH + q0) = v;
        }
    }
}

// ---------------- per-chunk states ----------------
__global__ __launch_bounds__(256) void k_states(const bf16_t* __restrict__ Xt,
                                                const bf16_t* __restrict__ Btr,
                                                const float* __restrict__ acum,
                                                float* __restrict__ states) {
    int blk = blockIdx.x;
    int bc = blk >> 5;
    int tid = threadIdx.x, wave = tid >> 6, lane = tid & 63;
    int l15 = lane & 15, quad = lane >> 4;
    __shared__ __align__(16) float sdec[CH];
    {
        size_t base = (size_t)blk * CH;
        float al = acum[base + CH - 1];
        sdec[tid] = __expf(al - acum[base + tid]);
    }
    __syncthreads();
    const bf16_t* Xb = Xt + (size_t)blk * 64 * CH;
    const bf16_t* Bb = Btr + (size_t)bc * DS * CH;
    f32x4 acc[4][2];
#pragma unroll
    for (int i = 0; i < 4; i++)
#pragma unroll
        for (int j = 0; j < 2; j++) acc[i][j] = (f32x4){0.f, 0.f, 0.f, 0.f};
#pragma unroll
    for (int ks = 0; ks < 8; ks++) {
        float d0[8];
#pragma unroll
        for (int j = 0; j < 8; j++) d0[j] = sdec[ks * 32 + quad * 8 + j];
        bf16x8 a[4], b[2];
#pragma unroll
        for (int mt = 0; mt < 4; mt++) {
            bf16x8 raw = *(const bf16x8*)(Xb + (size_t)(mt * 16 + l15) * CH + ks * 32 + quad * 8);
#pragma unroll
            for (int j = 0; j < 8; j++) a[mt][j] = (bf16_t)((float)raw[j] * d0[j]);
        }
#pragma unroll
        for (int nt = 0; nt < 2; nt++)
            b[nt] = *(const bf16x8*)(Bb + (size_t)(wave * 32 + nt * 16 + l15) * CH + ks * 32 + quad * 8);
#pragma unroll
        for (int mt = 0; mt < 4; mt++)
#pragma unroll
            for (int nt = 0; nt < 2; nt++)
                acc[mt][nt] = mfma16(a[mt], b[nt], acc[mt][nt]);
    }
#pragma unroll
    for (int mt = 0; mt < 4; mt++)
#pragma unroll
        for (int nt = 0; nt < 2; nt++)
#pragma unroll
            for (int r = 0; r < 4; r++)
                states[(size_t)blk * 64 * DS + (size_t)(mt * 16 + quad * 4 + r) * DS + wave * 32 + nt * 16 + l15] = acc[mt][nt][r];
}

// ---------------- parallel inter-chunk scan ----------------
__global__ __launch_bounds__(256) void k_scan(const float* __restrict__ states,
                                              const float* __restrict__ acum,
                                              bf16_t* __restrict__ prevb) {
    int blk = blockIdx.x;
    int bh = blk >> 5;
    int b = bh >> 5, h = bh & 31;
    int e = (blk & 31) * 256 + threadIdx.x;
    float prev = 0.f;
    for (int c = 0; c < NCH; c++) {
        size_t idx = (size_t)(b * NCH + c) * NH + h;
        float dec = __expf(acum[idx * CH + CH - 1]);
        size_t i = idx * 64 * DS + e;
        prevb[i] = (bf16_t)prev;
        prev = prev * dec + states[i];
    }
}

// ---------------- Sraw generator ----------------
__global__ __launch_bounds__(256) void k_sgen(const bf16_t* __restrict__ xBC,
                                              bf16_t* __restrict__ Sraw) {
    int t = blockIdx.x, bc = blockIdx.y;
    int qt = (t == 0) ? 1 : (t < 3) ? 2 : 3;
    int kt = t - qt * (qt - 1) / 2;
    int tid = threadIdx.x, wave = tid >> 6, lane = tid & 63;
    int l15 = lane & 15, quad = lane >> 4;
    const bf16_t* Cbase = xBC + (size_t)bc * CH * CD + DI + DS;
    const bf16_t* Bbase = xBC + (size_t)bc * CH * CD + DI;
    f32x4 acc[4];
#pragma unroll
    for (int j = 0; j < 4; j++) acc[j] = (f32x4){0.f, 0.f, 0.f, 0.f};
#pragma unroll
    for (int ks = 0; ks < 4; ks++) {
        bf16x8 a = *(const bf16x8*)(Cbase + (size_t)(qt * 64 + wave * 16 + l15) * CD + ks * 32 + quad * 8);
        bf16x8 b[4];
#pragma unroll
        for (int nt = 0; nt < 4; nt++)
            b[nt] = *(const bf16x8*)(Bbase + (size_t)(kt * 64 + nt * 16 + l15) * CD + ks * 32 + quad * 8);
#pragma unroll
        for (int nt = 0; nt < 4; nt++) acc[nt] = mfma16(a, b[nt], acc[nt]);
    }
    bf16_t* out = Sraw + ((size_t)bc * 6 + t) * 64 * 64;
#pragma unroll
    for (int nt = 0; nt < 4; nt++)
#pragma unroll
        for (int r = 0; r < 4; r++)
            out[(size_t)(wave * 16 + quad * 4 + r) * 64 + nt * 16 + l15] = (bf16_t)acc[nt][r];
}

// ---------------- fused chunk output (round-3 split form) ----------------
__global__ __launch_bounds__(256) void k_chunky(const bf16_t* __restrict__ xBC,
                                                const bf16_t* __restrict__ Xt,
                                                const bf16_t* __restrict__ prevb,
                                                const bf16_t* __restrict__ Sraw,
                                                const float* __restrict__ acum,
                                                const float* __restrict__ Dp,
                                                bf16_t* __restrict__ yf) {
    int blk = blockIdx.x;
    int bc = blk >> 5, h = blk & 31;
    int tid = threadIdx.x, wave = tid >> 6, lane = tid & 63;
    int l15 = lane & 15, quad = lane >> 4;
    __shared__ __align__(16) float sac[CH];
    __shared__ __align__(16) bf16_t sS[4][64][72];
    sac[tid] = acum[(size_t)blk * CH + tid];
    __syncthreads();

    const bf16_t* Cbase = xBC + (size_t)bc * CH * CD + DI + DS;
    const bf16_t* Bbase = xBC + (size_t)bc * CH * CD + DI;
    const bf16_t* XtB = Xt + (size_t)blk * 64 * CH;
    const bf16_t* pvB = prevb + (size_t)blk * 64 * DS;

    int qw = wave * 64;
    float refq = sac[qw];
    float s_ref = __expf(refq);
    f32x4 acc[4][4];
#pragma unroll
    for (int i = 0; i < 4; i++)
#pragma unroll
        for (int j = 0; j < 4; j++) acc[i][j] = (f32x4){0.f, 0.f, 0.f, 0.f};

    // ---- Y_off: acc = C @ prev^T (unscaled), then *= s_ref
#pragma unroll
    for (int ks = 0; ks < 4; ks++) {
        bf16x8 a[4], b[4];
#pragma unroll
        for (int mt = 0; mt < 4; mt++)
            a[mt] = *(const bf16x8*)(Cbase + (size_t)(qw + mt * 16 + l15) * CD + ks * 32 + quad * 8);
#pragma unroll
        for (int nt = 0; nt < 4; nt++)
            b[nt] = *(const bf16x8*)(pvB + (size_t)(nt * 16 + l15) * DS + ks * 32 + quad * 8);
#pragma unroll
        for (int mt = 0; mt < 4; mt++)
#pragma unroll
            for (int nt = 0; nt < 4; nt++)
                acc[mt][nt] = mfma16(a[mt], b[nt], acc[mt][nt]);
    }
#pragma unroll
    for (int mt = 0; mt < 4; mt++)
#pragma unroll
        for (int nt = 0; nt < 4; nt++)
#pragma unroll
            for (int r = 0; r < 4; r++) acc[mt][nt][r] *= s_ref;

    // ---- off-diagonal tiles: acc += Sraw @ (Xt * ek)^T
    for (int kt = 0; kt < wave; kt++) {
        const bf16_t* St = Sraw + ((size_t)bc * 6 + wave * (wave - 1) / 2 + kt) * 64 * 64;
#pragma unroll
        for (int ks = 0; ks < 2; ks++) {
            float ekv[8];
#pragma unroll
            for (int j = 0; j < 8; j++)
                ekv[j] = __expf(refq - sac[kt * 64 + ks * 32 + quad * 8 + j]);
            bf16x8 a[4], b[4];
#pragma unroll
            for (int mt = 0; mt < 4; mt++)
                a[mt] = *(const bf16x8*)(St + (size_t)(mt * 16 + l15) * 64 + ks * 32 + quad * 8);
#pragma unroll
            for (int nt = 0; nt < 4; nt++) {
                bf16x8 raw = *(const bf16x8*)(XtB + (size_t)(nt * 16 + l15) * CH + kt * 64 + ks * 32 + quad * 8);
#pragma unroll
                for (int j = 0; j < 8; j++) b[nt][j] = (bf16_t)((float)raw[j] * ekv[j]);
            }
#pragma unroll
            for (int mt = 0; mt < 4; mt++)
#pragma unroll
                for (int nt = 0; nt < 4; nt++)
                    acc[mt][nt] = mfma16(a[mt], b[nt], acc[mt][nt]);
        }
    }

    // ---- epilogue scaling by eq[q] = exp(acum[q] - refq)
    float sacq[4][4];
#pragma unroll
    for (int mt = 0; mt < 4; mt++)
#pragma unroll
        for (int r = 0; r < 4; r++) sacq[mt][r] = sac[qw + mt * 16 + quad * 4 + r];
#pragma unroll
    for (int mt = 0; mt < 4; mt++) {
        float eqv[4];
#pragma unroll
        for (int r = 0; r < 4; r++) eqv[r] = __expf(sacq[mt][r] - refq);
#pragma unroll
        for (int nt = 0; nt < 4; nt++)
#pragma unroll
            for (int r = 0; r < 4; r++) acc[mt][nt][r] *= eqv[r];
    }

    // ---- diagonal tile: S = C @ B^T here, per-element L, LDS round-trip
    {
        int kt = wave;
        f32x4 s2[4][4];
#pragma unroll
        for (int i = 0; i < 4; i++)
#pragma unroll
            for (int j = 0; j < 4; j++) s2[i][j] = (f32x4){0.f, 0.f, 0.f, 0.f};
#pragma unroll
        for (int ks = 0; ks < 4; ks++) {
            bf16x8 a[4], b[4];
#pragma unroll
            for (int mt = 0; mt < 4; mt++)
                a[mt] = *(const bf16x8*)(Cbase + (size_t)(qw + mt * 16 + l15) * CD + ks * 32 + quad * 8);
#pragma unroll
            for (int nt = 0; nt < 4; nt++)
                b[nt] = *(const bf16x8*)(Bbase + (size_t)(kt * 64 + nt * 16 + l15) * CD + ks * 32 + quad * 8);
#pragma unroll
            for (int mt = 0; mt < 4; mt++)
#pragma unroll
                for (int nt = 0; nt < 4; nt++)
                    s2[mt][nt] = mfma16(a[mt], b[nt], s2[mt][nt]);
        }
        float sack[4];
#pragma unroll
        for (int nt = 0; nt < 4; nt++) sack[nt] = sac[kt * 64 + nt * 16 + l15];
#pragma unroll
        for (int mt = 0; mt < 4; mt++)
#pragma unroll
            for (int nt = 0; nt < 4; nt++) {
                int kp = kt * 64 + nt * 16 + l15;
#pragma unroll
                for (int r = 0; r < 4; r++) {
                    int lq = mt * 16 + quad * 4 + r;
                    int q = qw + lq;
                    float v = (kp <= q) ? s2[mt][nt][r] * __expf(sacq[mt][r] - sack[nt]) : 0.f;
                    sS[wave][lq][nt * 16 + l15] = (bf16_t)v;
                }
            }
#pragma unroll
        for (int ks = 0; ks < 2; ks++) {
            bf16x8 a[4], b[4];
#pragma unroll
            for (int mt = 0; mt < 4; mt++)
                a[mt] = *(const bf16x8*)&sS[wave][mt * 16 + l15][ks * 32 + quad * 8];
#pragma unroll
            for (int nt = 0; nt < 4; nt++)
                b[nt] = *(const bf16x8*)(XtB + (size_t)(nt * 16 + l15) * CH + kt * 64 + ks * 32 + quad * 8);
#pragma unroll
            for (int mt = 0; mt < 4; mt++)
#pragma unroll
                for (int nt = 0; nt < 4; nt++)
                    acc[mt][nt] = mfma16(a[mt], b[nt], acc[mt][nt]);
        }
    }

    // ---- epilogue: + D*x, write bf16 y
    float Dh = Dp[h];
#pragma unroll
    for (int mt = 0; mt < 4; mt++)
#pragma unroll
        for (int nt = 0; nt < 4; nt++)
#pragma unroll
            for (int r = 0; r < 4; r++) {
                int q = qw + mt * 16 + quad * 4 + r;
                int p = nt * 16 + l15;
                size_t tok = (size_t)bc * CH + q;
                float xv = (float)xBC[tok * CD + h * 64 + p];
                yf[tok * DI + h * 64 + p] = (bf16_t)(acc[mt][nt][r] + Dh * xv);
            }
}

// ---------------- silu gate + RMS norm -> bf16 ----------------
__global__ __launch_bounds__(256) void k_gate(const bf16_t* __restrict__ yf,
                                              const bf16_t* __restrict__ zb,
                                              const float* __restrict__ nw,
                                              bf16_t* __restrict__ yg) {
    int tok = blockIdx.x, tid = threadIdx.x;
    float g[8];
    float ss = 0.f;
#pragma unroll
    for (int j = 0; j < 8; j++) {
        int d = tid + j * 256;
        float z = (float)zb[(size_t)tok * NPX + d];
        float yy = (float)yf[(size_t)tok * DI + d];
        float gg = yy * (z / (1.f + expf(-z)));
        g[j] = gg;
        ss += gg * gg;
    }
#pragma unroll
    for (int off = 32; off > 0; off >>= 1) ss += __shfl_down(ss, off);
    __shared__ __align__(16) float sw[4];
    int wave = tid >> 6, lane = tid & 63;
    if (lane == 0) sw[wave] = ss;
    __syncthreads();
    float tot = sw[0] + sw[1] + sw[2] + sw[3];
    float r = rsqrtf(tot / (float)DI + 1e-5f);
#pragma unroll
    for (int j = 0; j < 8; j++) {
        int d = tid + j * 256;
        yg[(size_t)tok * DI + d] = (bf16_t)(g[j] * r * nw[d]);
    }
}

extern "C" void kernel_launch(void* const* d_in, const int* in_sizes, int n_in,
                              void* d_out, int out_size, void* d_ws, size_t ws_size,
                              hipStream_t stream) {
    const float* u       = (const float*)d_in[0];
    const float* delta_t = (const float*)d_in[1];
    const float* W_in    = (const float*)d_in[2];
    const float* conv_w  = (const float*)d_in[3];
    const float* conv_b  = (const float*)d_in[4];
    const float* dt_bias = (const float*)d_in[5];
    const float* gamma   = (const float*)d_in[6];
    const float* A_log   = (const float*)d_in[7];
    const float* Dp      = (const float*)d_in[8];
    const float* norm_w  = (const float*)d_in[9];
    const float* W_out   = (const float*)d_in[10];
    float* out = (float*)d_out;

    char* p = (char*)d_ws;
    auto alloc = [&](size_t bytes) -> char* {
        char* r = p;
        p += (bytes + 255) & ~(size_t)255;
        return r;
    };
    bf16_t* zxBC    = (bf16_t*)alloc((size_t)NTOK * NPX * 2);
    bf16_t* Win_bf  = (bf16_t*)alloc((size_t)NP1 * DM * 2);
    bf16_t* Wout_bf = (bf16_t*)alloc((size_t)DM * DI * 2);
    float*  dtb     = (float*)alloc((size_t)NTOK * NH * 4);
    float*  acum    = (float*)alloc((size_t)NTOK * NH * 4);
    bf16_t* xBC_bf  = (bf16_t*)alloc((size_t)NTOK * CD * 2);
    bf16_t* Xt      = (bf16_t*)alloc((size_t)NTOK * DI * 2);
    bf16_t* poolA   = (bf16_t*)alloc((size_t)NTOK * DM * 2);
    bf16_t* Btr     = (bf16_t*)alloc((size_t)BSZ * NCH * DS * CH * 2);
    bf16_t* Sraw    = (bf16_t*)alloc((size_t)BSZ * NCH * 6 * 64 * 64 * 2);
    float*  dtf     = (float*)d_out;
    float*  states  = (float*)d_out;
    bf16_t* yf      = (bf16_t*)d_out;
    bf16_t* u_bf    = poolA;
    bf16_t* prevb   = poolA;
    bf16_t* yg_bf   = Xt;

    k_cvt_all<<<(CVT_U + CVT_WI + CVT_WO + 255) / 256, 256, 0, stream>>>(
        u, W_in, W_out, u_bf, Win_bf, Wout_bf);

    k_gemm256<<<dim3(NPX / 128, NTOK / 256), 256, 0, stream>>>(u_bf, Win_bf, zxBC, DM, NPX);
    k_gemm<float><<<dim3(1, NTOK / 128), 256, 0, stream>>>(u_bf, Win_bf + (size_t)NPX * DM, dtf, DM, 128);

    k_dtcum<<<BSZ * NCH * NH, CH, 0, stream>>>(dtf, delta_t, gamma, dt_bias, A_log, dtb, acum);
    k_conv<<<dim3(CD / 256, NTOK / 8), 256, 0, stream>>>(zxBC + DI, conv_w, conv_b, xBC_bf);
    k_sgen<<<dim3(6, BSZ * NCH), 256, 0, stream>>>(xBC_bf, Sraw);
    k_trans<<<dim3(34, BSZ * NCH), 256, 0, stream>>>(xBC_bf, dtb, Xt, Btr);
    k_states<<<BSZ * NCH * NH, 256, 0, stream>>>(Xt, Btr, acum, states);
    k_scan<<<BSZ * NH * 32, 256, 0, stream>>>(states, acum, prevb);
    k_chunky<<<BSZ * NCH * NH, 256, 0, stream>>>(xBC_bf, Xt, prevb, Sraw, acum, Dp, yf);
    k_gate<<<NTOK, 256, 0, stream>>>(yf, zxBC, norm_w, yg_bf);

    k_gemm<float><<<dim3(DM / 128, NTOK / 128), 256, 0, stream>>>(yg_bf, Wout_bf, out, DI, DM);
}

// Round 6
// 463.541 us; speedup vs baseline: 1.2008x; 1.2008x over previous
//
#include <hip/hip_runtime.h>
#include <hip/hip_bf16.h>
#include <math.h>

// ---- problem constants ----
#define DM    1024      // d_model
#define DIP   4384      // d_in_proj
#define NP1   4480      // padded in_proj rows
#define NPX   4352      // z + xBC columns (combined main GEMM width)
#define DI    2048      // d_inner
#define CD    2304      // conv dim
#define NH    32        // heads
#define HD    64        // head dim
#define DS    128       // d_state
#define CH    256       // chunk
#define NCH   16        // chunks per sequence
#define BSZ   2
#define SEQ   4096
#define NTOK  (BSZ*SEQ) // 8192

typedef __bf16 bf16_t;
typedef __attribute__((ext_vector_type(8))) __bf16 bf16x8;
typedef __attribute__((ext_vector_type(4))) float f32x4;

__device__ __forceinline__ f32x4 mfma16(bf16x8 a, bf16x8 b, f32x4 c) {
    return __builtin_amdgcn_mfma_f32_16x16x32_bf16(a, b, c, 0, 0, 0);
}

__device__ __forceinline__ void gload_lds16(const bf16_t* g, bf16_t* l) {
    __builtin_amdgcn_global_load_lds(
        (const __attribute__((address_space(1))) unsigned int*)g,
        (__attribute__((address_space(3))) unsigned int*)l, 16, 0, 0);
}

// ---------------- fused converts ----------------
#define CVT_U   (NTOK * DM)
#define CVT_WI  (NP1 * DM)
#define CVT_WO  (DM * DI)
__global__ void k_cvt_all(const float* __restrict__ u, const float* __restrict__ wi,
                          const float* __restrict__ wo,
                          bf16_t* __restrict__ u_bf, bf16_t* __restrict__ wi_bf,
                          bf16_t* __restrict__ wo_bf) {
    int i = blockIdx.x * 256 + threadIdx.x;
    if (i < CVT_U) {
        u_bf[i] = (bf16_t)u[i];
    } else if (i < CVT_U + CVT_WI) {
        int j = i - CVT_U;
        int r = j >> 10;  // DM=1024
        wi_bf[j] = (r < DIP) ? (bf16_t)wi[j] : (bf16_t)0.f;
    } else if (i < CVT_U + CVT_WI + CVT_WO) {
        int j = i - CVT_U - CVT_WI;
        wo_bf[j] = (bf16_t)wo[j];
    }
}

// ---------------- GEMM 128x128 (m97-style + XOR swizzle) — measured best: 114us, 0 conflicts.
// NOTE round-5: 256x128 tile regressed to 202us (occupancy 29%->10%, 1 block/CU). Do not enlarge.
template <typename OutT>
__global__ __launch_bounds__(256) void k_gemm(const bf16_t* __restrict__ A,
                                              const bf16_t* __restrict__ Bt,
                                              OutT* __restrict__ C, int K, int ldc) {
    __shared__ __align__(16) bf16_t sA[128 * 32];
    __shared__ __align__(16) bf16_t sB[128 * 32];
    int tid = threadIdx.x, wave = tid >> 6, lane = tid & 63;
    int l15 = lane & 15, quad = lane >> 4;
    int m0 = blockIdx.y * 128, n0 = blockIdx.x * 128;
    int wm = (wave & 1) * 64, wn = (wave >> 1) * 64;
    f32x4 acc[4][4];
#pragma unroll
    for (int i = 0; i < 4; i++)
#pragma unroll
        for (int j = 0; j < 4; j++) acc[i][j] = (f32x4){0.f, 0.f, 0.f, 0.f};

    int srow = lane >> 2, sc = lane & 3;
    int scol = (sc ^ ((srow >> 1) & 3)) * 8;
    const bf16_t* Ag0 = A + (size_t)(m0 + wave * 32 + srow) * K + scol;
    const bf16_t* Ag1 = Ag0 + (size_t)16 * K;
    const bf16_t* Bg0 = Bt + (size_t)(n0 + wave * 32 + srow) * K + scol;
    const bf16_t* Bg1 = Bg0 + (size_t)16 * K;
    bf16_t* lA0 = sA + (wave * 32) * 32;
    bf16_t* lA1 = sA + (wave * 32 + 16) * 32;
    bf16_t* lB0 = sB + (wave * 32) * 32;
    bf16_t* lB1 = sB + (wave * 32 + 16) * 32;
    int rchunk = (quad ^ ((l15 >> 1) & 3)) * 8;

    for (int k0 = 0; k0 < K; k0 += 32) {
        gload_lds16(Ag0 + k0, lA0);
        gload_lds16(Ag1 + k0, lA1);
        gload_lds16(Bg0 + k0, lB0);
        gload_lds16(Bg1 + k0, lB1);
        __syncthreads();
        bf16x8 af[4], bg[4];
#pragma unroll
        for (int mt = 0; mt < 4; mt++) af[mt] = *(const bf16x8*)&sA[(wm + mt * 16 + l15) * 32 + rchunk];
#pragma unroll
        for (int nt = 0; nt < 4; nt++) bg[nt] = *(const bf16x8*)&sB[(wn + nt * 16 + l15) * 32 + rchunk];
#pragma unroll
        for (int mt = 0; mt < 4; mt++)
#pragma unroll
            for (int nt = 0; nt < 4; nt++)
                acc[mt][nt] = mfma16(af[mt], bg[nt], acc[mt][nt]);
        __syncthreads();
    }
#pragma unroll
    for (int mt = 0; mt < 4; mt++)
#pragma unroll
        for (int nt = 0; nt < 4; nt++)
#pragma unroll
            for (int r = 0; r < 4; r++)
                C[(size_t)(m0 + wm + mt * 16 + quad * 4 + r) * ldc + n0 + wn + nt * 16 + l15] =
                    (OutT)acc[mt][nt][r];
}

// ---------------- skinny dt GEMM: dtf[tok][32] = u @ Wdt[32 x 1024]^T ----------------
// Wdt (64 KB) preloaded to LDS once; A staged per K-step. grid NTOK/128 = 64 blocks.
#define WPAD 1032
__global__ __launch_bounds__(256) void k_dtgemm(const bf16_t* __restrict__ A,
                                                const bf16_t* __restrict__ Wdt,
                                                float* __restrict__ dtf) {
    __shared__ __align__(16) bf16_t sW[32 * WPAD];
    __shared__ __align__(16) bf16_t sA[128 * 32];
    int tid = threadIdx.x, wave = tid >> 6, lane = tid & 63;
    int l15 = lane & 15, quad = lane >> 4;
    int m0 = blockIdx.x * 128;
#pragma unroll
    for (int it = 0; it < 16; it++) {
        int idx = it * 2048 + tid * 8;
        int r = idx >> 10, c = idx & 1023;
        *(bf16x8*)&sW[r * WPAD + c] = *(const bf16x8*)(Wdt + (size_t)r * DM + c);
    }
    f32x4 acc[2][2];
#pragma unroll
    for (int i = 0; i < 2; i++)
#pragma unroll
        for (int j = 0; j < 2; j++) acc[i][j] = (f32x4){0.f, 0.f, 0.f, 0.f};

    int srow = lane >> 2, sc = lane & 3;
    int scol = (sc ^ ((srow >> 1) & 3)) * 8;
    const bf16_t* Ag0 = A + (size_t)(m0 + wave * 32 + srow) * DM + scol;
    const bf16_t* Ag1 = Ag0 + (size_t)16 * DM;
    bf16_t* lA0 = sA + (wave * 32) * 32;
    bf16_t* lA1 = sA + (wave * 32 + 16) * 32;
    int rchunk = (quad ^ ((l15 >> 1) & 3)) * 8;

    for (int k0 = 0; k0 < DM; k0 += 32) {
        gload_lds16(Ag0 + k0, lA0);
        gload_lds16(Ag1 + k0, lA1);
        __syncthreads();
        bf16x8 af[2], bg[2];
#pragma unroll
        for (int mt = 0; mt < 2; mt++)
            af[mt] = *(const bf16x8*)&sA[(wave * 32 + mt * 16 + l15) * 32 + rchunk];
#pragma unroll
        for (int nt = 0; nt < 2; nt++)
            bg[nt] = *(const bf16x8*)&sW[(nt * 16 + l15) * WPAD + k0 + quad * 8];
#pragma unroll
        for (int mt = 0; mt < 2; mt++)
#pragma unroll
            for (int nt = 0; nt < 2; nt++)
                acc[mt][nt] = mfma16(af[mt], bg[nt], acc[mt][nt]);
        __syncthreads();
    }
#pragma unroll
    for (int mt = 0; mt < 2; mt++)
#pragma unroll
        for (int nt = 0; nt < 2; nt++)
#pragma unroll
            for (int r = 0; r < 4; r++)
                dtf[(size_t)(m0 + wave * 32 + mt * 16 + quad * 4 + r) * NH + nt * 16 + l15] =
                    acc[mt][nt][r];
}

// ---------------- dt + softplus + per-chunk cumsum of dt*A ----------------
__global__ __launch_bounds__(256) void k_dtcum(const float* __restrict__ dtf,
                                               const float* __restrict__ delta_t,
                                               const float* __restrict__ gamma,
                                               const float* __restrict__ dt_bias,
                                               const float* __restrict__ A_log,
                                               float* __restrict__ dtb, float* __restrict__ acum) {
    int blk = blockIdx.x;
    int h = blk & (NH - 1), bc = blk >> 5;
    int q = threadIdx.x;
    size_t tok = (size_t)bc * CH + q;
    float x = dtf[tok * NH + h] + gamma[h] * delta_t[tok] + dt_bias[h];
    float dt = (x > 20.f) ? x : log1pf(expf(x));
    float Ah = -expf(A_log[h]);
    __shared__ __align__(16) float s[CH];
    s[q] = dt * Ah;
    __syncthreads();
#pragma unroll
    for (int off = 1; off < CH; off <<= 1) {
        float v = (q >= off) ? s[q - off] : 0.f;
        __syncthreads();
        s[q] += v;
        __syncthreads();
    }
    dtb[(size_t)blk * CH + q] = dt;
    acum[(size_t)blk * CH + q] = s[q];
}

// ---------------- causal depthwise conv (4 taps) + bias + silu -> bf16 ----------------
__global__ __launch_bounds__(256) void k_conv(const bf16_t* __restrict__ zxp,
                                              const float* __restrict__ cw,
                                              const float* __restrict__ cb,
                                              bf16_t* __restrict__ xBC) {
    int ch = blockIdx.x * 256 + threadIdx.x;
    int tok0 = blockIdx.y * 8;
    int l0 = tok0 & (SEQ - 1);
    float w0 = cw[ch * 4], w1 = cw[ch * 4 + 1], w2 = cw[ch * 4 + 2], w3 = cw[ch * 4 + 3];
    float bias = cb[ch];
    float h0 = 0.f, h1 = 0.f, h2 = 0.f;
    if (l0 != 0) {
        h0 = (float)zxp[(size_t)(tok0 - 3) * NPX + ch];
        h1 = (float)zxp[(size_t)(tok0 - 2) * NPX + ch];
        h2 = (float)zxp[(size_t)(tok0 - 1) * NPX + ch];
    }
#pragma unroll
    for (int j = 0; j < 8; j++) {
        float cur = (float)zxp[(size_t)(tok0 + j) * NPX + ch];
        float acc = bias + h0 * w0 + h1 * w1 + h2 * w2 + cur * w3;
        float sv = acc / (1.f + expf(-acc));
        xBC[(size_t)(tok0 + j) * CD + ch] = (bf16_t)sv;
        h0 = h1; h1 = h2; h2 = cur;
    }
}

// ---------------- transpose + dt fold ----------------
__global__ __launch_bounds__(256) void k_trans(const bf16_t* __restrict__ xBC,
                                               const float* __restrict__ dtb,
                                               bf16_t* __restrict__ Xt, bf16_t* __restrict__ Btr) {
    int t = blockIdx.x, bc = blockIdx.y, tid = threadIdx.x;
    __shared__ __align__(16) bf16_t tile[CH][72];
    __shared__ __align__(16) float sdt[CH];
    int chbase = (t < 32) ? t * 64 : DI + (t - 32) * 64;
#pragma unroll
    for (int pp = 0; pp < 8; pp++) {
        int q = pp * 32 + (tid >> 3), col = (tid & 7) * 8;
        *(bf16x8*)&tile[q][col] = *(const bf16x8*)(xBC + (size_t)(bc * CH + q) * CD + chbase + col);
    }
    if (t < 32) sdt[tid] = dtb[(size_t)(bc * NH + t) * CH + tid];
    __syncthreads();
    int pl = tid >> 2, qg = tid & 3;
#pragma unroll
    for (int c8 = 0; c8 < 8; c8++) {
        int q0 = qg * 64 + c8 * 8;
        bf16x8 v;
        if (t < 32) {
#pragma unroll
            for (int j = 0; j < 8; j++) v[j] = (bf16_t)((float)tile[q0 + j][pl] * sdt[q0 + j]);
            size_t row = (size_t)(bc * NH + t) * 64 + pl;
            *(bf16x8*)(Xt + row * CH + q0) = v;
        } else {
#pragma unroll
            for (int j = 0; j < 8; j++) v[j] = tile[q0 + j][pl];
            size_t row = (size_t)bc * DS + (t - 32) * 64 + pl;
            *(bf16x8*)(Btr + row * CH + q0) = v;
        }
    }
}

// ---------------- per-chunk states (bf16 out) ----------------
__global__ __launch_bounds__(256) void k_states(const bf16_t* __restrict__ Xt,
                                                const bf16_t* __restrict__ Btr,
                                                const float* __restrict__ acum,
                                                bf16_t* __restrict__ states) {
    int blk = blockIdx.x;
    int bc = blk >> 5;
    int tid = threadIdx.x, wave = tid >> 6, lane = tid & 63;
    int l15 = lane & 15, quad = lane >> 4;
    __shared__ __align__(16) float sdec[CH];
    {
        size_t base = (size_t)blk * CH;
        float al = acum[base + CH - 1];
        sdec[tid] = __expf(al - acum[base + tid]);
    }
    __syncthreads();
    const bf16_t* Xb = Xt + (size_t)blk * 64 * CH;
    const bf16_t* Bb = Btr + (size_t)bc * DS * CH;
    f32x4 acc[4][2];
#pragma unroll
    for (int i = 0; i < 4; i++)
#pragma unroll
        for (int j = 0; j < 2; j++) acc[i][j] = (f32x4){0.f, 0.f, 0.f, 0.f};
#pragma unroll
    for (int ks = 0; ks < 8; ks++) {
        float d0[8];
#pragma unroll
        for (int j = 0; j < 8; j++) d0[j] = sdec[ks * 32 + quad * 8 + j];
        bf16x8 a[4], b[2];
#pragma unroll
        for (int mt = 0; mt < 4; mt++) {
            bf16x8 raw = *(const bf16x8*)(Xb + (size_t)(mt * 16 + l15) * CH + ks * 32 + quad * 8);
#pragma unroll
            for (int j = 0; j < 8; j++) a[mt][j] = (bf16_t)((float)raw[j] * d0[j]);
        }
#pragma unroll
        for (int nt = 0; nt < 2; nt++)
            b[nt] = *(const bf16x8*)(Bb + (size_t)(wave * 32 + nt * 16 + l15) * CH + ks * 32 + quad * 8);
#pragma unroll
        for (int mt = 0; mt < 4; mt++)
#pragma unroll
            for (int nt = 0; nt < 2; nt++)
                acc[mt][nt] = mfma16(a[mt], b[nt], acc[mt][nt]);
    }
#pragma unroll
    for (int mt = 0; mt < 4; mt++)
#pragma unroll
        for (int nt = 0; nt < 2; nt++)
#pragma unroll
            for (int r = 0; r < 4; r++)
                states[(size_t)blk * 64 * DS + (size_t)(mt * 16 + quad * 4 + r) * DS + wave * 32 + nt * 16 + l15] =
                    (bf16_t)acc[mt][nt][r];
}

// ---------------- parallel inter-chunk scan (bf16 states in, f32 accum) ----------------
__global__ __launch_bounds__(256) void k_scan(const bf16_t* __restrict__ states,
                                              const float* __restrict__ acum,
                                              bf16_t* __restrict__ prevb) {
    int blk = blockIdx.x;
    int bh = blk >> 5;
    int b = bh >> 5, h = bh & 31;
    int e = (blk & 31) * 256 + threadIdx.x;
    float prev = 0.f;
    for (int c = 0; c < NCH; c++) {
        size_t idx = (size_t)(b * NCH + c) * NH + h;
        float dec = __expf(acum[idx * CH + CH - 1]);
        size_t i = idx * 64 * DS + e;
        prevb[i] = (bf16_t)prev;
        prev = prev * dec + (float)states[i];
    }
}

// ---------------- Sraw generator ----------------
__global__ __launch_bounds__(256) void k_sgen(const bf16_t* __restrict__ xBC,
                                              bf16_t* __restrict__ Sraw) {
    int t = blockIdx.x, bc = blockIdx.y;
    int qt = (t == 0) ? 1 : (t < 3) ? 2 : 3;
    int kt = t - qt * (qt - 1) / 2;
    int tid = threadIdx.x, wave = tid >> 6, lane = tid & 63;
    int l15 = lane & 15, quad = lane >> 4;
    const bf16_t* Cbase = xBC + (size_t)bc * CH * CD + DI + DS;
    const bf16_t* Bbase = xBC + (size_t)bc * CH * CD + DI;
    f32x4 acc[4];
#pragma unroll
    for (int j = 0; j < 4; j++) acc[j] = (f32x4){0.f, 0.f, 0.f, 0.f};
#pragma unroll
    for (int ks = 0; ks < 4; ks++) {
        bf16x8 a = *(const bf16x8*)(Cbase + (size_t)(qt * 64 + wave * 16 + l15) * CD + ks * 32 + quad * 8);
        bf16x8 b[4];
#pragma unroll
        for (int nt = 0; nt < 4; nt++)
            b[nt] = *(const bf16x8*)(Bbase + (size_t)(kt * 64 + nt * 16 + l15) * CD + ks * 32 + quad * 8);
#pragma unroll
        for (int nt = 0; nt < 4; nt++) acc[nt] = mfma16(a, b[nt], acc[nt]);
    }
    bf16_t* out = Sraw + ((size_t)bc * 6 + t) * 64 * 64;
#pragma unroll
    for (int nt = 0; nt < 4; nt++)
#pragma unroll
        for (int r = 0; r < 4; r++)
            out[(size_t)(wave * 16 + quad * 4 + r) * 64 + nt * 16 + l15] = (bf16_t)acc[nt][r];
}

// ---------------- fused chunk output (round-3 split form — measured best) ----------------
__global__ __launch_bounds__(256) void k_chunky(const bf16_t* __restrict__ xBC,
                                                const bf16_t* __restrict__ Xt,
                                                const bf16_t* __restrict__ prevb,
                                                const bf16_t* __restrict__ Sraw,
                                                const float* __restrict__ acum,
                                                const float* __restrict__ Dp,
                                                bf16_t* __restrict__ yf) {
    int blk = blockIdx.x;
    int bc = blk >> 5, h = blk & 31;
    int tid = threadIdx.x, wave = tid >> 6, lane = tid & 63;
    int l15 = lane & 15, quad = lane >> 4;
    __shared__ __align__(16) float sac[CH];
    __shared__ __align__(16) bf16_t sS[4][64][72];
    sac[tid] = acum[(size_t)blk * CH + tid];
    __syncthreads();

    const bf16_t* Cbase = xBC + (size_t)bc * CH * CD + DI + DS;
    const bf16_t* Bbase = xBC + (size_t)bc * CH * CD + DI;
    const bf16_t* XtB = Xt + (size_t)blk * 64 * CH;
    const bf16_t* pvB = prevb + (size_t)blk * 64 * DS;

    int qw = wave * 64;
    float refq = sac[qw];
    float s_ref = __expf(refq);
    f32x4 acc[4][4];
#pragma unroll
    for (int i = 0; i < 4; i++)
#pragma unroll
        for (int j = 0; j < 4; j++) acc[i][j] = (f32x4){0.f, 0.f, 0.f, 0.f};

    // ---- Y_off: acc = C @ prev^T (unscaled), then *= s_ref
#pragma unroll
    for (int ks = 0; ks < 4; ks++) {
        bf16x8 a[4], b[4];
#pragma unroll
        for (int mt = 0; mt < 4; mt++)
            a[mt] = *(const bf16x8*)(Cbase + (size_t)(qw + mt * 16 + l15) * CD + ks * 32 + quad * 8);
#pragma unroll
        for (int nt = 0; nt < 4; nt++)
            b[nt] = *(const bf16x8*)(pvB + (size_t)(nt * 16 + l15) * DS + ks * 32 + quad * 8);
#pragma unroll
        for (int mt = 0; mt < 4; mt++)
#pragma unroll
            for (int nt = 0; nt < 4; nt++)
                acc[mt][nt] = mfma16(a[mt], b[nt], acc[mt][nt]);
    }
#pragma unroll
    for (int mt = 0; mt < 4; mt++)
#pragma unroll
        for (int nt = 0; nt < 4; nt++)
#pragma unroll
            for (int r = 0; r < 4; r++) acc[mt][nt][r] *= s_ref;

    // ---- off-diagonal tiles: acc += Sraw @ (Xt * ek)^T
    for (int kt = 0; kt < wave; kt++) {
        const bf16_t* St = Sraw + ((size_t)bc * 6 + wave * (wave - 1) / 2 + kt) * 64 * 64;
#pragma unroll
        for (int ks = 0; ks < 2; ks++) {
            float ekv[8];
#pragma unroll
            for (int j = 0; j < 8; j++)
                ekv[j] = __expf(refq - sac[kt * 64 + ks * 32 + quad * 8 + j]);
            bf16x8 a[4], b[4];
#pragma unroll
            for (int mt = 0; mt < 4; mt++)
                a[mt] = *(const bf16x8*)(St + (size_t)(mt * 16 + l15) * 64 + ks * 32 + quad * 8);
#pragma unroll
            for (int nt = 0; nt < 4; nt++) {
                bf16x8 raw = *(const bf16x8*)(XtB + (size_t)(nt * 16 + l15) * CH + kt * 64 + ks * 32 + quad * 8);
#pragma unroll
                for (int j = 0; j < 8; j++) b[nt][j] = (bf16_t)((float)raw[j] * ekv[j]);
            }
#pragma unroll
            for (int mt = 0; mt < 4; mt++)
#pragma unroll
                for (int nt = 0; nt < 4; nt++)
                    acc[mt][nt] = mfma16(a[mt], b[nt], acc[mt][nt]);
        }
    }

    // ---- epilogue scaling by eq[q] = exp(acum[q] - refq)
    float sacq[4][4];
#pragma unroll
    for (int mt = 0; mt < 4; mt++)
#pragma unroll
        for (int r = 0; r < 4; r++) sacq[mt][r] = sac[qw + mt * 16 + quad * 4 + r];
#pragma unroll
    for (int mt = 0; mt < 4; mt++) {
        float eqv[4];
#pragma unroll
        for (int r = 0; r < 4; r++) eqv[r] = __expf(sacq[mt][r] - refq);
#pragma unroll
        for (int nt = 0; nt < 4; nt++)
#pragma unroll
            for (int r = 0; r < 4; r++) acc[mt][nt][r] *= eqv[r];
    }

    // ---- diagonal tile: S = C @ B^T here, per-element L, LDS round-trip
    {
        int kt = wave;
        f32x4 s2[4][4];
#pragma unroll
        for (int i = 0; i < 4; i++)
#pragma unroll
            for (int j = 0; j < 4; j++) s2[i][j] = (f32x4){0.f, 0.f, 0.f, 0.f};
#pragma unroll
        for (int ks = 0; ks < 4; ks++) {
            bf16x8 a[4], b[4];
#pragma unroll
            for (int mt = 0; mt < 4; mt++)
                a[mt] = *(const bf16x8*)(Cbase + (size_t)(qw + mt * 16 + l15) * CD + ks * 32 + quad * 8);
#pragma unroll
            for (int nt = 0; nt < 4; nt++)
                b[nt] = *(const bf16x8*)(Bbase + (size_t)(kt * 64 + nt * 16 + l15) * CD + ks * 32 + quad * 8);
#pragma unroll
            for (int mt = 0; mt < 4; mt++)
#pragma unroll
                for (int nt = 0; nt < 4; nt++)
                    s2[mt][nt] = mfma16(a[mt], b[nt], s2[mt][nt]);
        }
        float sack[4];
#pragma unroll
        for (int nt = 0; nt < 4; nt++) sack[nt] = sac[kt * 64 + nt * 16 + l15];
#pragma unroll
        for (int mt = 0; mt < 4; mt++)
#pragma unroll
            for (int nt = 0; nt < 4; nt++) {
                int kp = kt * 64 + nt * 16 + l15;
#pragma unroll
                for (int r = 0; r < 4; r++) {
                    int lq = mt * 16 + quad * 4 + r;
                    int q = qw + lq;
                    float v = (kp <= q) ? s2[mt][nt][r] * __expf(sacq[mt][r] - sack[nt]) : 0.f;
                    sS[wave][lq][nt * 16 + l15] = (bf16_t)v;
                }
            }
#pragma unroll
        for (int ks = 0; ks < 2; ks++) {
            bf16x8 a[4], b[4];
#pragma unroll
            for (int mt = 0; mt < 4; mt++)
                a[mt] = *(const bf16x8*)&sS[wave][mt * 16 + l15][ks * 32 + quad * 8];
#pragma unroll
            for (int nt = 0; nt < 4; nt++)
                b[nt] = *(const bf16x8*)(XtB + (size_t)(nt * 16 + l15) * CH + kt * 64 + ks * 32 + quad * 8);
#pragma unroll
            for (int mt = 0; mt < 4; mt++)
#pragma unroll
                for (int nt = 0; nt < 4; nt++)
                    acc[mt][nt] = mfma16(a[mt], b[nt], acc[mt][nt]);
        }
    }

    // ---- epilogue: + D*x, write bf16 y
    float Dh = Dp[h];
#pragma unroll
    for (int mt = 0; mt < 4; mt++)
#pragma unroll
        for (int nt = 0; nt < 4; nt++)
#pragma unroll
            for (int r = 0; r < 4; r++) {
                int q = qw + mt * 16 + quad * 4 + r;
                int p = nt * 16 + l15;
                size_t tok = (size_t)bc * CH + q;
                float xv = (float)xBC[tok * CD + h * 64 + p];
                yf[tok * DI + h * 64 + p] = (bf16_t)(acc[mt][nt][r] + Dh * xv);
            }
}

// ---------------- silu gate + RMS norm -> bf16 ----------------
__global__ __launch_bounds__(256) void k_gate(const bf16_t* __restrict__ yf,
                                              const bf16_t* __restrict__ zb,
                                              const float* __restrict__ nw,
                                              bf16_t* __restrict__ yg) {
    int tok = blockIdx.x, tid = threadIdx.x;
    float g[8];
    float ss = 0.f;
#pragma unroll
    for (int j = 0; j < 8; j++) {
        int d = tid + j * 256;
        float z = (float)zb[(size_t)tok * NPX + d];
        float yy = (float)yf[(size_t)tok * DI + d];
        float gg = yy * (z / (1.f + expf(-z)));
        g[j] = gg;
        ss += gg * gg;
    }
#pragma unroll
    for (int off = 32; off > 0; off >>= 1) ss += __shfl_down(ss, off);
    __shared__ __align__(16) float sw[4];
    int wave = tid >> 6, lane = tid & 63;
    if (lane == 0) sw[wave] = ss;
    __syncthreads();
    float tot = sw[0] + sw[1] + sw[2] + sw[3];
    float r = rsqrtf(tot / (float)DI + 1e-5f);
#pragma unroll
    for (int j = 0; j < 8; j++) {
        int d = tid + j * 256;
        yg[(size_t)tok * DI + d] = (bf16_t)(g[j] * r * nw[d]);
    }
}

extern "C" void kernel_launch(void* const* d_in, const int* in_sizes, int n_in,
                              void* d_out, int out_size, void* d_ws, size_t ws_size,
                              hipStream_t stream) {
    const float* u       = (const float*)d_in[0];
    const float* delta_t = (const float*)d_in[1];
    const float* W_in    = (const float*)d_in[2];
    const float* conv_w  = (const float*)d_in[3];
    const float* conv_b  = (const float*)d_in[4];
    const float* dt_bias = (const float*)d_in[5];
    const float* gamma   = (const float*)d_in[6];
    const float* A_log   = (const float*)d_in[7];
    const float* Dp      = (const float*)d_in[8];
    const float* norm_w  = (const float*)d_in[9];
    const float* W_out   = (const float*)d_in[10];
    float* out = (float*)d_out;

    char* p = (char*)d_ws;
    auto alloc = [&](size_t bytes) -> char* {
        char* r = p;
        p += (bytes + 255) & ~(size_t)255;
        return r;
    };
    bf16_t* zxBC    = (bf16_t*)alloc((size_t)NTOK * NPX * 2);
    bf16_t* Win_bf  = (bf16_t*)alloc((size_t)NP1 * DM * 2);
    bf16_t* Wout_bf = (bf16_t*)alloc((size_t)DM * DI * 2);
    float*  dtb     = (float*)alloc((size_t)NTOK * NH * 4);
    float*  acum    = (float*)alloc((size_t)NTOK * NH * 4);
    bf16_t* xBC_bf  = (bf16_t*)alloc((size_t)NTOK * CD * 2);
    bf16_t* Xt      = (bf16_t*)alloc((size_t)NTOK * DI * 2);
    bf16_t* poolA   = (bf16_t*)alloc((size_t)NTOK * DM * 2);
    bf16_t* Btr     = (bf16_t*)alloc((size_t)BSZ * NCH * DS * CH * 2);
    bf16_t* Sraw    = (bf16_t*)alloc((size_t)BSZ * NCH * 6 * 64 * 64 * 2);
    // d_out scratch phases (stream-ordered, each dead before next use):
    float*  dtf     = (float*)d_out;            // 1 MB
    bf16_t* states  = (bf16_t*)d_out;           // 16.8 MB
    bf16_t* yf      = (bf16_t*)d_out;           // 33.5 MB
    bf16_t* u_bf    = poolA;
    bf16_t* prevb   = poolA;
    bf16_t* yg_bf   = Xt;

    k_cvt_all<<<(CVT_U + CVT_WI + CVT_WO + 255) / 256, 256, 0, stream>>>(
        u, W_in, W_out, u_bf, Win_bf, Wout_bf);

    k_gemm<bf16_t><<<dim3(NPX / 128, NTOK / 128), 256, 0, stream>>>(u_bf, Win_bf, zxBC, DM, NPX);
    k_dtgemm<<<NTOK / 128, 256, 0, stream>>>(u_bf, Win_bf + (size_t)NPX * DM, dtf);

    k_dtcum<<<BSZ * NCH * NH, CH, 0, stream>>>(dtf, delta_t, gamma, dt_bias, A_log, dtb, acum);
    k_conv<<<dim3(CD / 256, NTOK / 8), 256, 0, stream>>>(zxBC + DI, conv_w, conv_b, xBC_bf);
    k_sgen<<<dim3(6, BSZ * NCH), 256, 0, stream>>>(xBC_bf, Sraw);
    k_trans<<<dim3(34, BSZ * NCH), 256, 0, stream>>>(xBC_bf, dtb, Xt, Btr);
    k_states<<<BSZ * NCH * NH, 256, 0, stream>>>(Xt, Btr, acum, states);
    k_scan<<<BSZ * NH * 32, 256, 0, stream>>>(states, acum, prevb);
    k_chunky<<<BSZ * NCH * NH, 256, 0, stream>>>(xBC_bf, Xt, prevb, Sraw, acum, Dp, yf);
    k_gate<<<NTOK, 256, 0, stream>>>(yf, zxBC, norm_w, yg_bf);

    k_gemm<float><<<dim3(DM / 128, NTOK / 128), 256, 0, stream>>>(yg_bf, Wout_bf, out, DI, DM);
}

// Round 7
// 442.572 us; speedup vs baseline: 1.2577x; 1.0474x over previous
//
#include <hip/hip_runtime.h>
#include <hip/hip_bf16.h>
#include <math.h>

// ---- problem constants ----
#define DM    1024      // d_model
#define DIP   4384      // d_in_proj
#define NP1   4480      // padded in_proj rows
#define NPX   4352      // z + xBC columns (combined main GEMM width)
#define DI    2048      // d_inner
#define CD    2304      // conv dim
#define NH    32        // heads
#define HD    64        // head dim
#define DS    128       // d_state
#define CH    256       // chunk
#define NCH   16        // chunks per sequence
#define BSZ   2
#define SEQ   4096
#define NTOK  (BSZ*SEQ) // 8192

typedef __bf16 bf16_t;
typedef __attribute__((ext_vector_type(8))) __bf16 bf16x8;
typedef __attribute__((ext_vector_type(4))) float f32x4;

__device__ __forceinline__ f32x4 mfma16(bf16x8 a, bf16x8 b, f32x4 c) {
    return __builtin_amdgcn_mfma_f32_16x16x32_bf16(a, b, c, 0, 0, 0);
}

__device__ __forceinline__ void gload_lds16(const bf16_t* g, bf16_t* l) {
    __builtin_amdgcn_global_load_lds(
        (const __attribute__((address_space(1))) unsigned int*)g,
        (__attribute__((address_space(3))) unsigned int*)l, 16, 0, 0);
}

// ---------------- fused converts ----------------
#define CVT_U   (NTOK * DM)
#define CVT_WI  (NP1 * DM)
#define CVT_WO  (DM * DI)
__global__ void k_cvt_all(const float* __restrict__ u, const float* __restrict__ wi,
                          const float* __restrict__ wo,
                          bf16_t* __restrict__ u_bf, bf16_t* __restrict__ wi_bf,
                          bf16_t* __restrict__ wo_bf) {
    int i = blockIdx.x * 256 + threadIdx.x;
    if (i < CVT_U) {
        u_bf[i] = (bf16_t)u[i];
    } else if (i < CVT_U + CVT_WI) {
        int j = i - CVT_U;
        int r = j >> 10;  // DM=1024
        wi_bf[j] = (r < DIP) ? (bf16_t)wi[j] : (bf16_t)0.f;
    } else if (i < CVT_U + CVT_WI + CVT_WO) {
        int j = i - CVT_U - CVT_WI;
        wo_bf[j] = (bf16_t)wo[j];
    }
}

// ---------------- GEMM 128x128, BK=64: halves barrier count vs BK=32 (K-loop stall is the
// measured limiter: 28% MfmaUtil, 22% HBM, 0 conflicts at BK=32/114us).
// LDS 32KB (5 blk/CU cap; effective occupancy was ~2.3 blk — not binding).
// Swizzle: slot s of row r holds global chunk s^(r&7); staging key reduces to srow.
// NOTE round-5: 256x128 OUTPUT tile regressed (occupancy cliff). Output tile stays 128x128.
template <typename OutT>
__global__ __launch_bounds__(256) void k_gemm(const bf16_t* __restrict__ A,
                                              const bf16_t* __restrict__ Bt,
                                              OutT* __restrict__ C, int K, int ldc) {
    __shared__ __align__(16) bf16_t sA[128 * 64];
    __shared__ __align__(16) bf16_t sB[128 * 64];
    int tid = threadIdx.x, wave = tid >> 6, lane = tid & 63;
    int l15 = lane & 15, quad = lane >> 4;
    int m0 = blockIdx.y * 128, n0 = blockIdx.x * 128;
    int wm = (wave & 1) * 64, wn = (wave >> 1) * 64;
    f32x4 acc[4][4];
#pragma unroll
    for (int i = 0; i < 4; i++)
#pragma unroll
        for (int j = 0; j < 4; j++) acc[i][j] = (f32x4){0.f, 0.f, 0.f, 0.f};

    // staging: wave covers 32 rows in 4 issues of 8 rows; lane -> row srow=(l>>3), slot=(l&7)
    int srow = lane >> 3, sslot = lane & 7;
    int scol = (sslot ^ srow) * 8;  // r&7 == srow for every issue (issue stride 8)
    const bf16_t* Ag = A + (size_t)(m0 + wave * 32 + srow) * K + scol;
    const bf16_t* Bg = Bt + (size_t)(n0 + wave * 32 + srow) * K + scol;
    bf16_t* lA = sA + (wave * 32) * 64;
    bf16_t* lB = sB + (wave * 32) * 64;

    for (int k0 = 0; k0 < K; k0 += 64) {
#pragma unroll
        for (int i = 0; i < 4; i++) {
            gload_lds16(Ag + (size_t)(8 * i) * K + k0, lA + (8 * i) * 64);
            gload_lds16(Bg + (size_t)(8 * i) * K + k0, lB + (8 * i) * 64);
        }
        __syncthreads();
#pragma unroll
        for (int ks = 0; ks < 2; ks++) {
            int rslot = ((ks * 4 + quad) ^ (l15 & 7)) * 8;
            bf16x8 af[4], bg[4];
#pragma unroll
            for (int mt = 0; mt < 4; mt++) af[mt] = *(const bf16x8*)&sA[(wm + mt * 16 + l15) * 64 + rslot];
#pragma unroll
            for (int nt = 0; nt < 4; nt++) bg[nt] = *(const bf16x8*)&sB[(wn + nt * 16 + l15) * 64 + rslot];
#pragma unroll
            for (int mt = 0; mt < 4; mt++)
#pragma unroll
                for (int nt = 0; nt < 4; nt++)
                    acc[mt][nt] = mfma16(af[mt], bg[nt], acc[mt][nt]);
        }
        __syncthreads();
    }
#pragma unroll
    for (int mt = 0; mt < 4; mt++)
#pragma unroll
        for (int nt = 0; nt < 4; nt++)
#pragma unroll
            for (int r = 0; r < 4; r++)
                C[(size_t)(m0 + wm + mt * 16 + quad * 4 + r) * ldc + n0 + wn + nt * 16 + l15] =
                    (OutT)acc[mt][nt][r];
}

// ---------------- skinny dt GEMM (BK=32, proven) ----------------
#define WPAD 1032
__global__ __launch_bounds__(256) void k_dtgemm(const bf16_t* __restrict__ A,
                                                const bf16_t* __restrict__ Wdt,
                                                float* __restrict__ dtf) {
    __shared__ __align__(16) bf16_t sW[32 * WPAD];
    __shared__ __align__(16) bf16_t sA[128 * 32];
    int tid = threadIdx.x, wave = tid >> 6, lane = tid & 63;
    int l15 = lane & 15, quad = lane >> 4;
    int m0 = blockIdx.x * 128;
#pragma unroll
    for (int it = 0; it < 16; it++) {
        int idx = it * 2048 + tid * 8;
        int r = idx >> 10, c = idx & 1023;
        *(bf16x8*)&sW[r * WPAD + c] = *(const bf16x8*)(Wdt + (size_t)r * DM + c);
    }
    f32x4 acc[2][2];
#pragma unroll
    for (int i = 0; i < 2; i++)
#pragma unroll
        for (int j = 0; j < 2; j++) acc[i][j] = (f32x4){0.f, 0.f, 0.f, 0.f};

    int srow = lane >> 2, sc = lane & 3;
    int scol = (sc ^ ((srow >> 1) & 3)) * 8;
    const bf16_t* Ag0 = A + (size_t)(m0 + wave * 32 + srow) * DM + scol;
    const bf16_t* Ag1 = Ag0 + (size_t)16 * DM;
    bf16_t* lA0 = sA + (wave * 32) * 32;
    bf16_t* lA1 = sA + (wave * 32 + 16) * 32;
    int rchunk = (quad ^ ((l15 >> 1) & 3)) * 8;

    for (int k0 = 0; k0 < DM; k0 += 32) {
        gload_lds16(Ag0 + k0, lA0);
        gload_lds16(Ag1 + k0, lA1);
        __syncthreads();
        bf16x8 af[2], bg[2];
#pragma unroll
        for (int mt = 0; mt < 2; mt++)
            af[mt] = *(const bf16x8*)&sA[(wave * 32 + mt * 16 + l15) * 32 + rchunk];
#pragma unroll
        for (int nt = 0; nt < 2; nt++)
            bg[nt] = *(const bf16x8*)&sW[(nt * 16 + l15) * WPAD + k0 + quad * 8];
#pragma unroll
        for (int mt = 0; mt < 2; mt++)
#pragma unroll
            for (int nt = 0; nt < 2; nt++)
                acc[mt][nt] = mfma16(af[mt], bg[nt], acc[mt][nt]);
        __syncthreads();
    }
#pragma unroll
    for (int mt = 0; mt < 2; mt++)
#pragma unroll
        for (int nt = 0; nt < 2; nt++)
#pragma unroll
            for (int r = 0; r < 4; r++)
                dtf[(size_t)(m0 + wave * 32 + mt * 16 + quad * 4 + r) * NH + nt * 16 + l15] =
                    acc[mt][nt][r];
}

// ---------------- merged: dtcum (blocks 0..1023) + conv (blocks 1024..10239) ----------------
__global__ __launch_bounds__(256) void k_mid1(const float* __restrict__ dtf,
                                              const float* __restrict__ delta_t,
                                              const float* __restrict__ gamma,
                                              const float* __restrict__ dt_bias,
                                              const float* __restrict__ A_log,
                                              float* __restrict__ dtb, float* __restrict__ acum,
                                              const bf16_t* __restrict__ zxp,
                                              const float* __restrict__ cw,
                                              const float* __restrict__ cb,
                                              bf16_t* __restrict__ xBC) {
    int blk = blockIdx.x;
    int tid = threadIdx.x;
    if (blk < 1024) {
        // ---- dt + softplus + per-chunk cumsum of dt*A
        int h = blk & (NH - 1), bc = blk >> 5;
        int q = tid;
        size_t tok = (size_t)bc * CH + q;
        float x = dtf[tok * NH + h] + gamma[h] * delta_t[tok] + dt_bias[h];
        float dt = (x > 20.f) ? x : log1pf(expf(x));
        float Ah = -expf(A_log[h]);
        __shared__ __align__(16) float s[CH];
        s[q] = dt * Ah;
        __syncthreads();
#pragma unroll
        for (int off = 1; off < CH; off <<= 1) {
            float v = (q >= off) ? s[q - off] : 0.f;
            __syncthreads();
            s[q] += v;
            __syncthreads();
        }
        dtb[(size_t)blk * CH + q] = dt;
        acum[(size_t)blk * CH + q] = s[q];
    } else {
        // ---- causal depthwise conv (4 taps) + bias + silu -> bf16
        int t = blk - 1024;
        int ch = (t % 9) * 256 + tid;
        int tok0 = (t / 9) * 8;
        int l0 = tok0 & (SEQ - 1);
        float w0 = cw[ch * 4], w1 = cw[ch * 4 + 1], w2 = cw[ch * 4 + 2], w3 = cw[ch * 4 + 3];
        float bias = cb[ch];
        float h0 = 0.f, h1 = 0.f, h2 = 0.f;
        if (l0 != 0) {
            h0 = (float)zxp[(size_t)(tok0 - 3) * NPX + ch];
            h1 = (float)zxp[(size_t)(tok0 - 2) * NPX + ch];
            h2 = (float)zxp[(size_t)(tok0 - 1) * NPX + ch];
        }
#pragma unroll
        for (int j = 0; j < 8; j++) {
            float cur = (float)zxp[(size_t)(tok0 + j) * NPX + ch];
            float acc = bias + h0 * w0 + h1 * w1 + h2 * w2 + cur * w3;
            float sv = acc / (1.f + expf(-acc));
            xBC[(size_t)(tok0 + j) * CD + ch] = (bf16_t)sv;
            h0 = h1; h1 = h2; h2 = cur;
        }
    }
}

// ---------------- merged: sgen (blocks 0..191) + transpose/dt-fold (192..1279) ----------------
__global__ __launch_bounds__(256) void k_mid2(const bf16_t* __restrict__ xBC,
                                              const float* __restrict__ dtb,
                                              bf16_t* __restrict__ Xt, bf16_t* __restrict__ Btr,
                                              bf16_t* __restrict__ Sraw) {
    int blk = blockIdx.x;
    int tid = threadIdx.x, wave = tid >> 6, lane = tid & 63;
    int l15 = lane & 15, quad = lane >> 4;
    if (blk < 192) {
        // ---- Sraw: 6 off-diagonal 64x64 tiles of S = C @ B^T per chunk
        int t = blk % 6, bc = blk / 6;
        int qt = (t == 0) ? 1 : (t < 3) ? 2 : 3;
        int kt = t - qt * (qt - 1) / 2;
        const bf16_t* Cbase = xBC + (size_t)bc * CH * CD + DI + DS;
        const bf16_t* Bbase = xBC + (size_t)bc * CH * CD + DI;
        f32x4 acc[4];
#pragma unroll
        for (int j = 0; j < 4; j++) acc[j] = (f32x4){0.f, 0.f, 0.f, 0.f};
#pragma unroll
        for (int ks = 0; ks < 4; ks++) {
            bf16x8 a = *(const bf16x8*)(Cbase + (size_t)(qt * 64 + wave * 16 + l15) * CD + ks * 32 + quad * 8);
            bf16x8 b[4];
#pragma unroll
            for (int nt = 0; nt < 4; nt++)
                b[nt] = *(const bf16x8*)(Bbase + (size_t)(kt * 64 + nt * 16 + l15) * CD + ks * 32 + quad * 8);
#pragma unroll
            for (int nt = 0; nt < 4; nt++) acc[nt] = mfma16(a, b[nt], acc[nt]);
        }
        bf16_t* out = Sraw + ((size_t)bc * 6 + t) * 64 * 64;
#pragma unroll
        for (int nt = 0; nt < 4; nt++)
#pragma unroll
            for (int r = 0; r < 4; r++)
                out[(size_t)(wave * 16 + quad * 4 + r) * 64 + nt * 16 + l15] = (bf16_t)acc[nt][r];
    } else {
        // ---- transpose + dt fold
        int tr = blk - 192;
        int t = tr % 34, bc = tr / 34;
        __shared__ __align__(16) bf16_t tile[CH][72];
        __shared__ __align__(16) float sdt[CH];
        int chbase = (t < 32) ? t * 64 : DI + (t - 32) * 64;
#pragma unroll
        for (int pp = 0; pp < 8; pp++) {
            int q = pp * 32 + (tid >> 3), col = (tid & 7) * 8;
            *(bf16x8*)&tile[q][col] = *(const bf16x8*)(xBC + (size_t)(bc * CH + q) * CD + chbase + col);
        }
        if (t < 32) sdt[tid] = dtb[(size_t)(bc * NH + t) * CH + tid];
        __syncthreads();
        int pl = tid >> 2, qg = tid & 3;
#pragma unroll
        for (int c8 = 0; c8 < 8; c8++) {
            int q0 = qg * 64 + c8 * 8;
            bf16x8 v;
            if (t < 32) {
#pragma unroll
                for (int j = 0; j < 8; j++) v[j] = (bf16_t)((float)tile[q0 + j][pl] * sdt[q0 + j]);
                size_t row = (size_t)(bc * NH + t) * 64 + pl;
                *(bf16x8*)(Xt + row * CH + q0) = v;
            } else {
#pragma unroll
                for (int j = 0; j < 8; j++) v[j] = tile[q0 + j][pl];
                size_t row = (size_t)bc * DS + (t - 32) * 64 + pl;
                *(bf16x8*)(Btr + row * CH + q0) = v;
            }
        }
    }
}

// ---------------- per-chunk states (bf16 out) ----------------
__global__ __launch_bounds__(256) void k_states(const bf16_t* __restrict__ Xt,
                                                const bf16_t* __restrict__ Btr,
                                                const float* __restrict__ acum,
                                                bf16_t* __restrict__ states) {
    int blk = blockIdx.x;
    int bc = blk >> 5;
    int tid = threadIdx.x, wave = tid >> 6, lane = tid & 63;
    int l15 = lane & 15, quad = lane >> 4;
    __shared__ __align__(16) float sdec[CH];
    {
        size_t base = (size_t)blk * CH;
        float al = acum[base + CH - 1];
        sdec[tid] = __expf(al - acum[base + tid]);
    }
    __syncthreads();
    const bf16_t* Xb = Xt + (size_t)blk * 64 * CH;
    const bf16_t* Bb = Btr + (size_t)bc * DS * CH;
    f32x4 acc[4][2];
#pragma unroll
    for (int i = 0; i < 4; i++)
#pragma unroll
        for (int j = 0; j < 2; j++) acc[i][j] = (f32x4){0.f, 0.f, 0.f, 0.f};
#pragma unroll
    for (int ks = 0; ks < 8; ks++) {
        float d0[8];
#pragma unroll
        for (int j = 0; j < 8; j++) d0[j] = sdec[ks * 32 + quad * 8 + j];
        bf16x8 a[4], b[2];
#pragma unroll
        for (int mt = 0; mt < 4; mt++) {
            bf16x8 raw = *(const bf16x8*)(Xb + (size_t)(mt * 16 + l15) * CH + ks * 32 + quad * 8);
#pragma unroll
            for (int j = 0; j < 8; j++) a[mt][j] = (bf16_t)((float)raw[j] * d0[j]);
        }
#pragma unroll
        for (int nt = 0; nt < 2; nt++)
            b[nt] = *(const bf16x8*)(Bb + (size_t)(wave * 32 + nt * 16 + l15) * CH + ks * 32 + quad * 8);
#pragma unroll
        for (int mt = 0; mt < 4; mt++)
#pragma unroll
            for (int nt = 0; nt < 2; nt++)
                acc[mt][nt] = mfma16(a[mt], b[nt], acc[mt][nt]);
    }
#pragma unroll
    for (int mt = 0; mt < 4; mt++)
#pragma unroll
        for (int nt = 0; nt < 2; nt++)
#pragma unroll
            for (int r = 0; r < 4; r++)
                states[(size_t)blk * 64 * DS + (size_t)(mt * 16 + quad * 4 + r) * DS + wave * 32 + nt * 16 + l15] =
                    (bf16_t)acc[mt][nt][r];
}

// ---------------- parallel inter-chunk scan ----------------
__global__ __launch_bounds__(256) void k_scan(const bf16_t* __restrict__ states,
                                              const float* __restrict__ acum,
                                              bf16_t* __restrict__ prevb) {
    int blk = blockIdx.x;
    int bh = blk >> 5;
    int b = bh >> 5, h = bh & 31;
    int e = (blk & 31) * 256 + threadIdx.x;
    float prev = 0.f;
    for (int c = 0; c < NCH; c++) {
        size_t idx = (size_t)(b * NCH + c) * NH + h;
        float dec = __expf(acum[idx * CH + CH - 1]);
        size_t i = idx * 64 * DS + e;
        prevb[i] = (bf16_t)prev;
        prev = prev * dec + (float)states[i];
    }
}

// ---------------- fused chunk output (round-3 split form — measured best) ----------------
__global__ __launch_bounds__(256) void k_chunky(const bf16_t* __restrict__ xBC,
                                                const bf16_t* __restrict__ Xt,
                                                const bf16_t* __restrict__ prevb,
                                                const bf16_t* __restrict__ Sraw,
                                                const float* __restrict__ acum,
                                                const float* __restrict__ Dp,
                                                bf16_t* __restrict__ yf) {
    int blk = blockIdx.x;
    int bc = blk >> 5, h = blk & 31;
    int tid = threadIdx.x, wave = tid >> 6, lane = tid & 63;
    int l15 = lane & 15, quad = lane >> 4;
    __shared__ __align__(16) float sac[CH];
    __shared__ __align__(16) bf16_t sS[4][64][72];
    sac[tid] = acum[(size_t)blk * CH + tid];
    __syncthreads();

    const bf16_t* Cbase = xBC + (size_t)bc * CH * CD + DI + DS;
    const bf16_t* Bbase = xBC + (size_t)bc * CH * CD + DI;
    const bf16_t* XtB = Xt + (size_t)blk * 64 * CH;
    const bf16_t* pvB = prevb + (size_t)blk * 64 * DS;

    int qw = wave * 64;
    float refq = sac[qw];
    float s_ref = __expf(refq);
    f32x4 acc[4][4];
#pragma unroll
    for (int i = 0; i < 4; i++)
#pragma unroll
        for (int j = 0; j < 4; j++) acc[i][j] = (f32x4){0.f, 0.f, 0.f, 0.f};

    // ---- Y_off: acc = C @ prev^T (unscaled), then *= s_ref
#pragma unroll
    for (int ks = 0; ks < 4; ks++) {
        bf16x8 a[4], b[4];
#pragma unroll
        for (int mt = 0; mt < 4; mt++)
            a[mt] = *(const bf16x8*)(Cbase + (size_t)(qw + mt * 16 + l15) * CD + ks * 32 + quad * 8);
#pragma unroll
        for (int nt = 0; nt < 4; nt++)
            b[nt] = *(const bf16x8*)(pvB + (size_t)(nt * 16 + l15) * DS + ks * 32 + quad * 8);
#pragma unroll
        for (int mt = 0; mt < 4; mt++)
#pragma unroll
            for (int nt = 0; nt < 4; nt++)
                acc[mt][nt] = mfma16(a[mt], b[nt], acc[mt][nt]);
    }
#pragma unroll
    for (int mt = 0; mt < 4; mt++)
#pragma unroll
        for (int nt = 0; nt < 4; nt++)
#pragma unroll
            for (int r = 0; r < 4; r++) acc[mt][nt][r] *= s_ref;

    // ---- off-diagonal tiles: acc += Sraw @ (Xt * ek)^T
    for (int kt = 0; kt < wave; kt++) {
        const bf16_t* St = Sraw + ((size_t)bc * 6 + wave * (wave - 1) / 2 + kt) * 64 * 64;
#pragma unroll
        for (int ks = 0; ks < 2; ks++) {
            float ekv[8];
#pragma unroll
            for (int j = 0; j < 8; j++)
                ekv[j] = __expf(refq - sac[kt * 64 + ks * 32 + quad * 8 + j]);
            bf16x8 a[4], b[4];
#pragma unroll
            for (int mt = 0; mt < 4; mt++)
                a[mt] = *(const bf16x8*)(St + (size_t)(mt * 16 + l15) * 64 + ks * 32 + quad * 8);
#pragma unroll
            for (int nt = 0; nt < 4; nt++) {
                bf16x8 raw = *(const bf16x8*)(XtB + (size_t)(nt * 16 + l15) * CH + kt * 64 + ks * 32 + quad * 8);
#pragma unroll
                for (int j = 0; j < 8; j++) b[nt][j] = (bf16_t)((float)raw[j] * ekv[j]);
            }
#pragma unroll
            for (int mt = 0; mt < 4; mt++)
#pragma unroll
                for (int nt = 0; nt < 4; nt++)
                    acc[mt][nt] = mfma16(a[mt], b[nt], acc[mt][nt]);
        }
    }

    // ---- epilogue scaling by eq[q] = exp(acum[q] - refq)
    float sacq[4][4];
#pragma unroll
    for (int mt = 0; mt < 4; mt++)
#pragma unroll
        for (int r = 0; r < 4; r++) sacq[mt][r] = sac[qw + mt * 16 + quad * 4 + r];
#pragma unroll
    for (int mt = 0; mt < 4; mt++) {
        float eqv[4];
#pragma unroll
        for (int r = 0; r < 4; r++) eqv[r] = __expf(sacq[mt][r] - refq);
#pragma unroll
        for (int nt = 0; nt < 4; nt++)
#pragma unroll
            for (int r = 0; r < 4; r++) acc[mt][nt][r] *= eqv[r];
    }

    // ---- diagonal tile: S = C @ B^T here, per-element L, LDS round-trip
    {
        int kt = wave;
        f32x4 s2[4][4];
#pragma unroll
        for (int i = 0; i < 4; i++)
#pragma unroll
            for (int j = 0; j < 4; j++) s2[i][j] = (f32x4){0.f, 0.f, 0.f, 0.f};
#pragma unroll
        for (int ks = 0; ks < 4; ks++) {
            bf16x8 a[4], b[4];
#pragma unroll
            for (int mt = 0; mt < 4; mt++)
                a[mt] = *(const bf16x8*)(Cbase + (size_t)(qw + mt * 16 + l15) * CD + ks * 32 + quad * 8);
#pragma unroll
            for (int nt = 0; nt < 4; nt++)
                b[nt] = *(const bf16x8*)(Bbase + (size_t)(kt * 64 + nt * 16 + l15) * CD + ks * 32 + quad * 8);
#pragma unroll
            for (int mt = 0; mt < 4; mt++)
#pragma unroll
                for (int nt = 0; nt < 4; nt++)
                    s2[mt][nt] = mfma16(a[mt], b[nt], s2[mt][nt]);
        }
        float sack[4];
#pragma unroll
        for (int nt = 0; nt < 4; nt++) sack[nt] = sac[kt * 64 + nt * 16 + l15];
#pragma unroll
        for (int mt = 0; mt < 4; mt++)
#pragma unroll
            for (int nt = 0; nt < 4; nt++) {
                int kp = kt * 64 + nt * 16 + l15;
#pragma unroll
                for (int r = 0; r < 4; r++) {
                    int lq = mt * 16 + quad * 4 + r;
                    int q = qw + lq;
                    float v = (kp <= q) ? s2[mt][nt][r] * __expf(sacq[mt][r] - sack[nt]) : 0.f;
                    sS[wave][lq][nt * 16 + l15] = (bf16_t)v;
                }
            }
#pragma unroll
        for (int ks = 0; ks < 2; ks++) {
            bf16x8 a[4], b[4];
#pragma unroll
            for (int mt = 0; mt < 4; mt++)
                a[mt] = *(const bf16x8*)&sS[wave][mt * 16 + l15][ks * 32 + quad * 8];
#pragma unroll
            for (int nt = 0; nt < 4; nt++)
                b[nt] = *(const bf16x8*)(XtB + (size_t)(nt * 16 + l15) * CH + kt * 64 + ks * 32 + quad * 8);
#pragma unroll
            for (int mt = 0; mt < 4; mt++)
#pragma unroll
                for (int nt = 0; nt < 4; nt++)
                    acc[mt][nt] = mfma16(a[mt], b[nt], acc[mt][nt]);
        }
    }

    // ---- epilogue: + D*x, write bf16 y
    float Dh = Dp[h];
#pragma unroll
    for (int mt = 0; mt < 4; mt++)
#pragma unroll
        for (int nt = 0; nt < 4; nt++)
#pragma unroll
            for (int r = 0; r < 4; r++) {
                int q = qw + mt * 16 + quad * 4 + r;
                int p = nt * 16 + l15;
                size_t tok = (size_t)bc * CH + q;
                float xv = (float)xBC[tok * CD + h * 64 + p];
                yf[tok * DI + h * 64 + p] = (bf16_t)(acc[mt][nt][r] + Dh * xv);
            }
}

// ---------------- silu gate + RMS norm -> bf16 ----------------
__global__ __launch_bounds__(256) void k_gate(const bf16_t* __restrict__ yf,
                                              const bf16_t* __restrict__ zb,
                                              const float* __restrict__ nw,
                                              bf16_t* __restrict__ yg) {
    int tok = blockIdx.x, tid = threadIdx.x;
    float g[8];
    float ss = 0.f;
#pragma unroll
    for (int j = 0; j < 8; j++) {
        int d = tid + j * 256;
        float z = (float)zb[(size_t)tok * NPX + d];
        float yy = (float)yf[(size_t)tok * DI + d];
        float gg = yy * (z / (1.f + expf(-z)));
        g[j] = gg;
        ss += gg * gg;
    }
#pragma unroll
    for (int off = 32; off > 0; off >>= 1) ss += __shfl_down(ss, off);
    __shared__ __align__(16) float sw[4];
    int wave = tid >> 6, lane = tid & 63;
    if (lane == 0) sw[wave] = ss;
    __syncthreads();
    float tot = sw[0] + sw[1] + sw[2] + sw[3];
    float r = rsqrtf(tot / (float)DI + 1e-5f);
#pragma unroll
    for (int j = 0; j < 8; j++) {
        int d = tid + j * 256;
        yg[(size_t)tok * DI + d] = (bf16_t)(g[j] * r * nw[d]);
    }
}

extern "C" void kernel_launch(void* const* d_in, const int* in_sizes, int n_in,
                              void* d_out, int out_size, void* d_ws, size_t ws_size,
                              hipStream_t stream) {
    const float* u       = (const float*)d_in[0];
    const float* delta_t = (const float*)d_in[1];
    const float* W_in    = (const float*)d_in[2];
    const float* conv_w  = (const float*)d_in[3];
    const float* conv_b  = (const float*)d_in[4];
    const float* dt_bias = (const float*)d_in[5];
    const float* gamma   = (const float*)d_in[6];
    const float* A_log   = (const float*)d_in[7];
    const float* Dp      = (const float*)d_in[8];
    const float* norm_w  = (const float*)d_in[9];
    const float* W_out   = (const float*)d_in[10];
    float* out = (float*)d_out;

    char* p = (char*)d_ws;
    auto alloc = [&](size_t bytes) -> char* {
        char* r = p;
        p += (bytes + 255) & ~(size_t)255;
        return r;
    };
    bf16_t* zxBC    = (bf16_t*)alloc((size_t)NTOK * NPX * 2);
    bf16_t* Win_bf  = (bf16_t*)alloc((size_t)NP1 * DM * 2);
    bf16_t* Wout_bf = (bf16_t*)alloc((size_t)DM * DI * 2);
    float*  dtb     = (float*)alloc((size_t)NTOK * NH * 4);
    float*  acum    = (float*)alloc((size_t)NTOK * NH * 4);
    bf16_t* xBC_bf  = (bf16_t*)alloc((size_t)NTOK * CD * 2);
    bf16_t* Xt      = (bf16_t*)alloc((size_t)NTOK * DI * 2);
    bf16_t* poolA   = (bf16_t*)alloc((size_t)NTOK * DM * 2);
    bf16_t* Btr     = (bf16_t*)alloc((size_t)BSZ * NCH * DS * CH * 2);
    bf16_t* Sraw    = (bf16_t*)alloc((size_t)BSZ * NCH * 6 * 64 * 64 * 2);
    // d_out scratch phases (stream-ordered, each dead before next use):
    float*  dtf     = (float*)d_out;            // 1 MB
    bf16_t* states  = (bf16_t*)d_out;           // 16.8 MB
    bf16_t* yf      = (bf16_t*)d_out;           // 33.5 MB
    bf16_t* u_bf    = poolA;
    bf16_t* prevb   = poolA;
    bf16_t* yg_bf   = Xt;

    k_cvt_all<<<(CVT_U + CVT_WI + CVT_WO + 255) / 256, 256, 0, stream>>>(
        u, W_in, W_out, u_bf, Win_bf, Wout_bf);

    k_gemm<bf16_t><<<dim3(NPX / 128, NTOK / 128), 256, 0, stream>>>(u_bf, Win_bf, zxBC, DM, NPX);
    k_dtgemm<<<NTOK / 128, 256, 0, stream>>>(u_bf, Win_bf + (size_t)NPX * DM, dtf);

    k_mid1<<<1024 + 9 * (NTOK / 8), 256, 0, stream>>>(dtf, delta_t, gamma, dt_bias, A_log,
                                                      dtb, acum, zxBC + DI, conv_w, conv_b, xBC_bf);
    k_mid2<<<192 + 34 * BSZ * NCH, 256, 0, stream>>>(xBC_bf, dtb, Xt, Btr, Sraw);
    k_states<<<BSZ * NCH * NH, 256, 0, stream>>>(Xt, Btr, acum, states);
    k_scan<<<BSZ * NH * 32, 256, 0, stream>>>(states, acum, prevb);
    k_chunky<<<BSZ * NCH * NH, 256, 0, stream>>>(xBC_bf, Xt, prevb, Sraw, acum, Dp, yf);
    k_gate<<<NTOK, 256, 0, stream>>>(yf, zxBC, norm_w, yg_bf);

    k_gemm<float><<<dim3(DM / 128, NTOK / 128), 256, 0, stream>>>(yg_bf, Wout_bf, out, DI, DM);
}

// Round 8
// 422.536 us; speedup vs baseline: 1.3173x; 1.0474x over previous
//
#include <hip/hip_runtime.h>
#include <hip/hip_bf16.h>
#include <math.h>

// ---- problem constants ----
#define DM    1024      // d_model
#define DIP   4384      // d_in_proj
#define NP1   4480      // padded in_proj rows
#define NPX   4352      // z + xBC columns (combined main GEMM width)
#define DI    2048      // d_inner
#define CD    2304      // conv dim
#define NH    32        // heads
#define HD    64        // head dim
#define DS    128       // d_state
#define CH    256       // chunk
#define NCH   16        // chunks per sequence
#define BSZ   2
#define SEQ   4096
#define NTOK  (BSZ*SEQ) // 8192

typedef __bf16 bf16_t;
typedef __attribute__((ext_vector_type(8))) __bf16 bf16x8;
typedef __attribute__((ext_vector_type(4))) float f32x4;

__device__ __forceinline__ f32x4 mfma16(bf16x8 a, bf16x8 b, f32x4 c) {
    return __builtin_amdgcn_mfma_f32_16x16x32_bf16(a, b, c, 0, 0, 0);
}

__device__ __forceinline__ void gload_lds16(const bf16_t* g, bf16_t* l) {
    __builtin_amdgcn_global_load_lds(
        (const __attribute__((address_space(1))) unsigned int*)g,
        (__attribute__((address_space(3))) unsigned int*)l, 16, 0, 0);
}

// ---------------- fused converts ----------------
#define CVT_U   (NTOK * DM)
#define CVT_WI  (NP1 * DM)
#define CVT_WO  (DM * DI)
__global__ void k_cvt_all(const float* __restrict__ u, const float* __restrict__ wi,
                          const float* __restrict__ wo,
                          bf16_t* __restrict__ u_bf, bf16_t* __restrict__ wi_bf,
                          bf16_t* __restrict__ wo_bf) {
    int i = blockIdx.x * 256 + threadIdx.x;
    if (i < CVT_U) {
        u_bf[i] = (bf16_t)u[i];
    } else if (i < CVT_U + CVT_WI) {
        int j = i - CVT_U;
        int r = j >> 10;  // DM=1024
        wi_bf[j] = (r < DIP) ? (bf16_t)wi[j] : (bf16_t)0.f;
    } else if (i < CVT_U + CVT_WI + CVT_WO) {
        int j = i - CVT_U - CVT_WI;
        wo_bf[j] = (bf16_t)wo[j];
    }
}

// ---------------- GEMM 128x128, BK=64 + XCD-aware 4x2 super-tiling ----------------
// Round-7: BK=64 = 95.7us, MfmaUtil 33%, 0 conflicts. FETCH 151MB vs 26MB ideal: A fetched
// ~8x (once per XCD) under default round-robin block->XCD. Fix: 1D grid, i&7 selects
// (m-group of mtiles/4, n-group of ntiles/2) so each XCD works a private 2D super-tile;
// t=i>>3 sweeps m inner (B-tile fetched once/XCD, A-group ~4MB L2-resident).
// NOTE round-5: 256x128 output tile regressed (occupancy cliff). Output tile stays 128x128.
template <typename OutT>
__global__ __launch_bounds__(256) void k_gemm(const bf16_t* __restrict__ A,
                                              const bf16_t* __restrict__ Bt,
                                              OutT* __restrict__ C, int K, int ldc,
                                              int mtiles, int ntiles) {
    __shared__ __align__(16) bf16_t sA[128 * 64];
    __shared__ __align__(16) bf16_t sB[128 * 64];
    int tid = threadIdx.x, wave = tid >> 6, lane = tid & 63;
    int l15 = lane & 15, quad = lane >> 4;

    // XCD-aware super-tile decode (mtiles % 4 == 0, ntiles % 2 == 0)
    int i = blockIdx.x;
    int x = i & 7, t = i >> 3;
    int mtg = mtiles >> 2, ntg = ntiles >> 1;
    int mti = (x >> 1) * mtg + (t % mtg);
    int nti = (x & 1) * ntg + (t / mtg);
    int m0 = mti * 128, n0 = nti * 128;

    int wm = (wave & 1) * 64, wn = (wave >> 1) * 64;
    f32x4 acc[4][4];
#pragma unroll
    for (int ii = 0; ii < 4; ii++)
#pragma unroll
        for (int j = 0; j < 4; j++) acc[ii][j] = (f32x4){0.f, 0.f, 0.f, 0.f};

    // staging: wave covers 32 rows in 4 issues of 8 rows; lane -> row srow=(l>>3), slot=(l&7)
    int srow = lane >> 3, sslot = lane & 7;
    int scol = (sslot ^ srow) * 8;  // r&7 == srow for every issue (issue stride 8)
    const bf16_t* Ag = A + (size_t)(m0 + wave * 32 + srow) * K + scol;
    const bf16_t* Bg = Bt + (size_t)(n0 + wave * 32 + srow) * K + scol;
    bf16_t* lA = sA + (wave * 32) * 64;
    bf16_t* lB = sB + (wave * 32) * 64;

    for (int k0 = 0; k0 < K; k0 += 64) {
#pragma unroll
        for (int ii = 0; ii < 4; ii++) {
            gload_lds16(Ag + (size_t)(8 * ii) * K + k0, lA + (8 * ii) * 64);
            gload_lds16(Bg + (size_t)(8 * ii) * K + k0, lB + (8 * ii) * 64);
        }
        __syncthreads();
#pragma unroll
        for (int ks = 0; ks < 2; ks++) {
            int rslot = ((ks * 4 + quad) ^ (l15 & 7)) * 8;
            bf16x8 af[4], bg[4];
#pragma unroll
            for (int mt = 0; mt < 4; mt++) af[mt] = *(const bf16x8*)&sA[(wm + mt * 16 + l15) * 64 + rslot];
#pragma unroll
            for (int nt = 0; nt < 4; nt++) bg[nt] = *(const bf16x8*)&sB[(wn + nt * 16 + l15) * 64 + rslot];
#pragma unroll
            for (int mt = 0; mt < 4; mt++)
#pragma unroll
                for (int nt = 0; nt < 4; nt++)
                    acc[mt][nt] = mfma16(af[mt], bg[nt], acc[mt][nt]);
        }
        __syncthreads();
    }
#pragma unroll
    for (int mt = 0; mt < 4; mt++)
#pragma unroll
        for (int nt = 0; nt < 4; nt++)
#pragma unroll
            for (int r = 0; r < 4; r++)
                C[(size_t)(m0 + wm + mt * 16 + quad * 4 + r) * ldc + n0 + wn + nt * 16 + l15] =
                    (OutT)acc[mt][nt][r];
}

// ---------------- skinny dt GEMM (BK=32, proven) ----------------
#define WPAD 1032
__global__ __launch_bounds__(256) void k_dtgemm(const bf16_t* __restrict__ A,
                                                const bf16_t* __restrict__ Wdt,
                                                float* __restrict__ dtf) {
    __shared__ __align__(16) bf16_t sW[32 * WPAD];
    __shared__ __align__(16) bf16_t sA[128 * 32];
    int tid = threadIdx.x, wave = tid >> 6, lane = tid & 63;
    int l15 = lane & 15, quad = lane >> 4;
    int m0 = blockIdx.x * 128;
#pragma unroll
    for (int it = 0; it < 16; it++) {
        int idx = it * 2048 + tid * 8;
        int r = idx >> 10, c = idx & 1023;
        *(bf16x8*)&sW[r * WPAD + c] = *(const bf16x8*)(Wdt + (size_t)r * DM + c);
    }
    f32x4 acc[2][2];
#pragma unroll
    for (int i = 0; i < 2; i++)
#pragma unroll
        for (int j = 0; j < 2; j++) acc[i][j] = (f32x4){0.f, 0.f, 0.f, 0.f};

    int srow = lane >> 2, sc = lane & 3;
    int scol = (sc ^ ((srow >> 1) & 3)) * 8;
    const bf16_t* Ag0 = A + (size_t)(m0 + wave * 32 + srow) * DM + scol;
    const bf16_t* Ag1 = Ag0 + (size_t)16 * DM;
    bf16_t* lA0 = sA + (wave * 32) * 32;
    bf16_t* lA1 = sA + (wave * 32 + 16) * 32;
    int rchunk = (quad ^ ((l15 >> 1) & 3)) * 8;

    for (int k0 = 0; k0 < DM; k0 += 32) {
        gload_lds16(Ag0 + k0, lA0);
        gload_lds16(Ag1 + k0, lA1);
        __syncthreads();
        bf16x8 af[2], bg[2];
#pragma unroll
        for (int mt = 0; mt < 2; mt++)
            af[mt] = *(const bf16x8*)&sA[(wave * 32 + mt * 16 + l15) * 32 + rchunk];
#pragma unroll
        for (int nt = 0; nt < 2; nt++)
            bg[nt] = *(const bf16x8*)&sW[(nt * 16 + l15) * WPAD + k0 + quad * 8];
#pragma unroll
        for (int mt = 0; mt < 2; mt++)
#pragma unroll
            for (int nt = 0; nt < 2; nt++)
                acc[mt][nt] = mfma16(af[mt], bg[nt], acc[mt][nt]);
        __syncthreads();
    }
#pragma unroll
    for (int mt = 0; mt < 2; mt++)
#pragma unroll
        for (int nt = 0; nt < 2; nt++)
#pragma unroll
            for (int r = 0; r < 4; r++)
                dtf[(size_t)(m0 + wave * 32 + mt * 16 + quad * 4 + r) * NH + nt * 16 + l15] =
                    acc[mt][nt][r];
}

// ---------------- merged: dtcum (blocks 0..1023) + conv (blocks 1024..10239) ----------------
__global__ __launch_bounds__(256) void k_mid1(const float* __restrict__ dtf,
                                              const float* __restrict__ delta_t,
                                              const float* __restrict__ gamma,
                                              const float* __restrict__ dt_bias,
                                              const float* __restrict__ A_log,
                                              float* __restrict__ dtb, float* __restrict__ acum,
                                              const bf16_t* __restrict__ zxp,
                                              const float* __restrict__ cw,
                                              const float* __restrict__ cb,
                                              bf16_t* __restrict__ xBC) {
    int blk = blockIdx.x;
    int tid = threadIdx.x;
    if (blk < 1024) {
        int h = blk & (NH - 1), bc = blk >> 5;
        int q = tid;
        size_t tok = (size_t)bc * CH + q;
        float x = dtf[tok * NH + h] + gamma[h] * delta_t[tok] + dt_bias[h];
        float dt = (x > 20.f) ? x : log1pf(expf(x));
        float Ah = -expf(A_log[h]);
        __shared__ __align__(16) float s[CH];
        s[q] = dt * Ah;
        __syncthreads();
#pragma unroll
        for (int off = 1; off < CH; off <<= 1) {
            float v = (q >= off) ? s[q - off] : 0.f;
            __syncthreads();
            s[q] += v;
            __syncthreads();
        }
        dtb[(size_t)blk * CH + q] = dt;
        acum[(size_t)blk * CH + q] = s[q];
    } else {
        int t = blk - 1024;
        int ch = (t % 9) * 256 + tid;
        int tok0 = (t / 9) * 8;
        int l0 = tok0 & (SEQ - 1);
        float w0 = cw[ch * 4], w1 = cw[ch * 4 + 1], w2 = cw[ch * 4 + 2], w3 = cw[ch * 4 + 3];
        float bias = cb[ch];
        float h0 = 0.f, h1 = 0.f, h2 = 0.f;
        if (l0 != 0) {
            h0 = (float)zxp[(size_t)(tok0 - 3) * NPX + ch];
            h1 = (float)zxp[(size_t)(tok0 - 2) * NPX + ch];
            h2 = (float)zxp[(size_t)(tok0 - 1) * NPX + ch];
        }
#pragma unroll
        for (int j = 0; j < 8; j++) {
            float cur = (float)zxp[(size_t)(tok0 + j) * NPX + ch];
            float acc = bias + h0 * w0 + h1 * w1 + h2 * w2 + cur * w3;
            float sv = acc / (1.f + expf(-acc));
            xBC[(size_t)(tok0 + j) * CD + ch] = (bf16_t)sv;
            h0 = h1; h1 = h2; h2 = cur;
        }
    }
}

// ---------------- merged: sgen (blocks 0..191) + transpose/dt-fold (192..1279) ----------------
__global__ __launch_bounds__(256) void k_mid2(const bf16_t* __restrict__ xBC,
                                              const float* __restrict__ dtb,
                                              bf16_t* __restrict__ Xt, bf16_t* __restrict__ Btr,
                                              bf16_t* __restrict__ Sraw) {
    int blk = blockIdx.x;
    int tid = threadIdx.x, wave = tid >> 6, lane = tid & 63;
    int l15 = lane & 15, quad = lane >> 4;
    if (blk < 192) {
        int t = blk % 6, bc = blk / 6;
        int qt = (t == 0) ? 1 : (t < 3) ? 2 : 3;
        int kt = t - qt * (qt - 1) / 2;
        const bf16_t* Cbase = xBC + (size_t)bc * CH * CD + DI + DS;
        const bf16_t* Bbase = xBC + (size_t)bc * CH * CD + DI;
        f32x4 acc[4];
#pragma unroll
        for (int j = 0; j < 4; j++) acc[j] = (f32x4){0.f, 0.f, 0.f, 0.f};
#pragma unroll
        for (int ks = 0; ks < 4; ks++) {
            bf16x8 a = *(const bf16x8*)(Cbase + (size_t)(qt * 64 + wave * 16 + l15) * CD + ks * 32 + quad * 8);
            bf16x8 b[4];
#pragma unroll
            for (int nt = 0; nt < 4; nt++)
                b[nt] = *(const bf16x8*)(Bbase + (size_t)(kt * 64 + nt * 16 + l15) * CD + ks * 32 + quad * 8);
#pragma unroll
            for (int nt = 0; nt < 4; nt++) acc[nt] = mfma16(a, b[nt], acc[nt]);
        }
        bf16_t* out = Sraw + ((size_t)bc * 6 + t) * 64 * 64;
#pragma unroll
        for (int nt = 0; nt < 4; nt++)
#pragma unroll
            for (int r = 0; r < 4; r++)
                out[(size_t)(wave * 16 + quad * 4 + r) * 64 + nt * 16 + l15] = (bf16_t)acc[nt][r];
    } else {
        int tr = blk - 192;
        int t = tr % 34, bc = tr / 34;
        __shared__ __align__(16) bf16_t tile[CH][72];
        __shared__ __align__(16) float sdt[CH];
        int chbase = (t < 32) ? t * 64 : DI + (t - 32) * 64;
#pragma unroll
        for (int pp = 0; pp < 8; pp++) {
            int q = pp * 32 + (tid >> 3), col = (tid & 7) * 8;
            *(bf16x8*)&tile[q][col] = *(const bf16x8*)(xBC + (size_t)(bc * CH + q) * CD + chbase + col);
        }
        if (t < 32) sdt[tid] = dtb[(size_t)(bc * NH + t) * CH + tid];
        __syncthreads();
        int pl = tid >> 2, qg = tid & 3;
#pragma unroll
        for (int c8 = 0; c8 < 8; c8++) {
            int q0 = qg * 64 + c8 * 8;
            bf16x8 v;
            if (t < 32) {
#pragma unroll
                for (int j = 0; j < 8; j++) v[j] = (bf16_t)((float)tile[q0 + j][pl] * sdt[q0 + j]);
                size_t row = (size_t)(bc * NH + t) * 64 + pl;
                *(bf16x8*)(Xt + row * CH + q0) = v;
            } else {
#pragma unroll
                for (int j = 0; j < 8; j++) v[j] = tile[q0 + j][pl];
                size_t row = (size_t)bc * DS + (t - 32) * 64 + pl;
                *(bf16x8*)(Btr + row * CH + q0) = v;
            }
        }
    }
}

// ---------------- per-chunk states (bf16 out) ----------------
__global__ __launch_bounds__(256) void k_states(const bf16_t* __restrict__ Xt,
                                                const bf16_t* __restrict__ Btr,
                                                const float* __restrict__ acum,
                                                bf16_t* __restrict__ states) {
    int blk = blockIdx.x;
    int bc = blk >> 5;
    int tid = threadIdx.x, wave = tid >> 6, lane = tid & 63;
    int l15 = lane & 15, quad = lane >> 4;
    __shared__ __align__(16) float sdec[CH];
    {
        size_t base = (size_t)blk * CH;
        float al = acum[base + CH - 1];
        sdec[tid] = __expf(al - acum[base + tid]);
    }
    __syncthreads();
    const bf16_t* Xb = Xt + (size_t)blk * 64 * CH;
    const bf16_t* Bb = Btr + (size_t)bc * DS * CH;
    f32x4 acc[4][2];
#pragma unroll
    for (int i = 0; i < 4; i++)
#pragma unroll
        for (int j = 0; j < 2; j++) acc[i][j] = (f32x4){0.f, 0.f, 0.f, 0.f};
#pragma unroll
    for (int ks = 0; ks < 8; ks++) {
        float d0[8];
#pragma unroll
        for (int j = 0; j < 8; j++) d0[j] = sdec[ks * 32 + quad * 8 + j];
        bf16x8 a[4], b[2];
#pragma unroll
        for (int mt = 0; mt < 4; mt++) {
            bf16x8 raw = *(const bf16x8*)(Xb + (size_t)(mt * 16 + l15) * CH + ks * 32 + quad * 8);
#pragma unroll
            for (int j = 0; j < 8; j++) a[mt][j] = (bf16_t)((float)raw[j] * d0[j]);
        }
#pragma unroll
        for (int nt = 0; nt < 2; nt++)
            b[nt] = *(const bf16x8*)(Bb + (size_t)(wave * 32 + nt * 16 + l15) * CH + ks * 32 + quad * 8);
#pragma unroll
        for (int mt = 0; mt < 4; mt++)
#pragma unroll
            for (int nt = 0; nt < 2; nt++)
                acc[mt][nt] = mfma16(a[mt], b[nt], acc[mt][nt]);
    }
#pragma unroll
    for (int mt = 0; mt < 4; mt++)
#pragma unroll
        for (int nt = 0; nt < 2; nt++)
#pragma unroll
            for (int r = 0; r < 4; r++)
                states[(size_t)blk * 64 * DS + (size_t)(mt * 16 + quad * 4 + r) * DS + wave * 32 + nt * 16 + l15] =
                    (bf16_t)acc[mt][nt][r];
}

// ---------------- parallel inter-chunk scan ----------------
__global__ __launch_bounds__(256) void k_scan(const bf16_t* __restrict__ states,
                                              const float* __restrict__ acum,
                                              bf16_t* __restrict__ prevb) {
    int blk = blockIdx.x;
    int bh = blk >> 5;
    int b = bh >> 5, h = bh & 31;
    int e = (blk & 31) * 256 + threadIdx.x;
    float prev = 0.f;
    for (int c = 0; c < NCH; c++) {
        size_t idx = (size_t)(b * NCH + c) * NH + h;
        float dec = __expf(acum[idx * CH + CH - 1]);
        size_t i = idx * 64 * DS + e;
        prevb[i] = (bf16_t)prev;
        prev = prev * dec + (float)states[i];
    }
}

// ---------------- fused chunk output (round-3 split form — measured best) ----------------
__global__ __launch_bounds__(256) void k_chunky(const bf16_t* __restrict__ xBC,
                                                const bf16_t* __restrict__ Xt,
                                                const bf16_t* __restrict__ prevb,
                                                const bf16_t* __restrict__ Sraw,
                                                const float* __restrict__ acum,
                                                const float* __restrict__ Dp,
                                                bf16_t* __restrict__ yf) {
    int blk = blockIdx.x;
    int bc = blk >> 5, h = blk & 31;
    int tid = threadIdx.x, wave = tid >> 6, lane = tid & 63;
    int l15 = lane & 15, quad = lane >> 4;
    __shared__ __align__(16) float sac[CH];
    __shared__ __align__(16) bf16_t sS[4][64][72];
    sac[tid] = acum[(size_t)blk * CH + tid];
    __syncthreads();

    const bf16_t* Cbase = xBC + (size_t)bc * CH * CD + DI + DS;
    const bf16_t* Bbase = xBC + (size_t)bc * CH * CD + DI;
    const bf16_t* XtB = Xt + (size_t)blk * 64 * CH;
    const bf16_t* pvB = prevb + (size_t)blk * 64 * DS;

    int qw = wave * 64;
    float refq = sac[qw];
    float s_ref = __expf(refq);
    f32x4 acc[4][4];
#pragma unroll
    for (int i = 0; i < 4; i++)
#pragma unroll
        for (int j = 0; j < 4; j++) acc[i][j] = (f32x4){0.f, 0.f, 0.f, 0.f};

    // ---- Y_off: acc = C @ prev^T (unscaled), then *= s_ref
#pragma unroll
    for (int ks = 0; ks < 4; ks++) {
        bf16x8 a[4], b[4];
#pragma unroll
        for (int mt = 0; mt < 4; mt++)
            a[mt] = *(const bf16x8*)(Cbase + (size_t)(qw + mt * 16 + l15) * CD + ks * 32 + quad * 8);
#pragma unroll
        for (int nt = 0; nt < 4; nt++)
            b[nt] = *(const bf16x8*)(pvB + (size_t)(nt * 16 + l15) * DS + ks * 32 + quad * 8);
#pragma unroll
        for (int mt = 0; mt < 4; mt++)
#pragma unroll
            for (int nt = 0; nt < 4; nt++)
                acc[mt][nt] = mfma16(a[mt], b[nt], acc[mt][nt]);
    }
#pragma unroll
    for (int mt = 0; mt < 4; mt++)
#pragma unroll
        for (int nt = 0; nt < 4; nt++)
#pragma unroll
            for (int r = 0; r < 4; r++) acc[mt][nt][r] *= s_ref;

    // ---- off-diagonal tiles: acc += Sraw @ (Xt * ek)^T
    for (int kt = 0; kt < wave; kt++) {
        const bf16_t* St = Sraw + ((size_t)bc * 6 + wave * (wave - 1) / 2 + kt) * 64 * 64;
#pragma unroll
        for (int ks = 0; ks < 2; ks++) {
            float ekv[8];
#pragma unroll
            for (int j = 0; j < 8; j++)
                ekv[j] = __expf(refq - sac[kt * 64 + ks * 32 + quad * 8 + j]);
            bf16x8 a[4], b[4];
#pragma unroll
            for (int mt = 0; mt < 4; mt++)
                a[mt] = *(const bf16x8*)(St + (size_t)(mt * 16 + l15) * 64 + ks * 32 + quad * 8);
#pragma unroll
            for (int nt = 0; nt < 4; nt++) {
                bf16x8 raw = *(const bf16x8*)(XtB + (size_t)(nt * 16 + l15) * CH + kt * 64 + ks * 32 + quad * 8);
#pragma unroll
                for (int j = 0; j < 8; j++) b[nt][j] = (bf16_t)((float)raw[j] * ekv[j]);
            }
#pragma unroll
            for (int mt = 0; mt < 4; mt++)
#pragma unroll
                for (int nt = 0; nt < 4; nt++)
                    acc[mt][nt] = mfma16(a[mt], b[nt], acc[mt][nt]);
        }
    }

    // ---- epilogue scaling by eq[q] = exp(acum[q] - refq)
    float sacq[4][4];
#pragma unroll
    for (int mt = 0; mt < 4; mt++)
#pragma unroll
        for (int r = 0; r < 4; r++) sacq[mt][r] = sac[qw + mt * 16 + quad * 4 + r];
#pragma unroll
    for (int mt = 0; mt < 4; mt++) {
        float eqv[4];
#pragma unroll
        for (int r = 0; r < 4; r++) eqv[r] = __expf(sacq[mt][r] - refq);
#pragma unroll
        for (int nt = 0; nt < 4; nt++)
#pragma unroll
            for (int r = 0; r < 4; r++) acc[mt][nt][r] *= eqv[r];
    }

    // ---- diagonal tile: S = C @ B^T here, per-element L, LDS round-trip
    {
        int kt = wave;
        f32x4 s2[4][4];
#pragma unroll
        for (int i = 0; i < 4; i++)
#pragma unroll
            for (int j = 0; j < 4; j++) s2[i][j] = (f32x4){0.f, 0.f, 0.f, 0.f};
#pragma unroll
        for (int ks = 0; ks < 4; ks++) {
            bf16x8 a[4], b[4];
#pragma unroll
            for (int mt = 0; mt < 4; mt++)
                a[mt] = *(const bf16x8*)(Cbase + (size_t)(qw + mt * 16 + l15) * CD + ks * 32 + quad * 8);
#pragma unroll
            for (int nt = 0; nt < 4; nt++)
                b[nt] = *(const bf16x8*)(Bbase + (size_t)(kt * 64 + nt * 16 + l15) * CD + ks * 32 + quad * 8);
#pragma unroll
            for (int mt = 0; mt < 4; mt++)
#pragma unroll
                for (int nt = 0; nt < 4; nt++)
                    s2[mt][nt] = mfma16(a[mt], b[nt], s2[mt][nt]);
        }
        float sack[4];
#pragma unroll
        for (int nt = 0; nt < 4; nt++) sack[nt] = sac[kt * 64 + nt * 16 + l15];
#pragma unroll
        for (int mt = 0; mt < 4; mt++)
#pragma unroll
            for (int nt = 0; nt < 4; nt++) {
                int kp = kt * 64 + nt * 16 + l15;
#pragma unroll
                for (int r = 0; r < 4; r++) {
                    int lq = mt * 16 + quad * 4 + r;
                    int q = qw + lq;
                    float v = (kp <= q) ? s2[mt][nt][r] * __expf(sacq[mt][r] - sack[nt]) : 0.f;
                    sS[wave][lq][nt * 16 + l15] = (bf16_t)v;
                }
            }
#pragma unroll
        for (int ks = 0; ks < 2; ks++) {
            bf16x8 a[4], b[4];
#pragma unroll
            for (int mt = 0; mt < 4; mt++)
                a[mt] = *(const bf16x8*)&sS[wave][mt * 16 + l15][ks * 32 + quad * 8];
#pragma unroll
            for (int nt = 0; nt < 4; nt++)
                b[nt] = *(const bf16x8*)(XtB + (size_t)(nt * 16 + l15) * CH + kt * 64 + ks * 32 + quad * 8);
#pragma unroll
            for (int mt = 0; mt < 4; mt++)
#pragma unroll
                for (int nt = 0; nt < 4; nt++)
                    acc[mt][nt] = mfma16(a[mt], b[nt], acc[mt][nt]);
        }
    }

    // ---- epilogue: + D*x, write bf16 y
    float Dh = Dp[h];
#pragma unroll
    for (int mt = 0; mt < 4; mt++)
#pragma unroll
        for (int nt = 0; nt < 4; nt++)
#pragma unroll
            for (int r = 0; r < 4; r++) {
                int q = qw + mt * 16 + quad * 4 + r;
                int p = nt * 16 + l15;
                size_t tok = (size_t)bc * CH + q;
                float xv = (float)xBC[tok * CD + h * 64 + p];
                yf[tok * DI + h * 64 + p] = (bf16_t)(acc[mt][nt][r] + Dh * xv);
            }
}

// ---------------- silu gate + RMS norm -> bf16 ----------------
__global__ __launch_bounds__(256) void k_gate(const bf16_t* __restrict__ yf,
                                              const bf16_t* __restrict__ zb,
                                              const float* __restrict__ nw,
                                              bf16_t* __restrict__ yg) {
    int tok = blockIdx.x, tid = threadIdx.x;
    float g[8];
    float ss = 0.f;
#pragma unroll
    for (int j = 0; j < 8; j++) {
        int d = tid + j * 256;
        float z = (float)zb[(size_t)tok * NPX + d];
        float yy = (float)yf[(size_t)tok * DI + d];
        float gg = yy * (z / (1.f + expf(-z)));
        g[j] = gg;
        ss += gg * gg;
    }
#pragma unroll
    for (int off = 32; off > 0; off >>= 1) ss += __shfl_down(ss, off);
    __shared__ __align__(16) float sw[4];
    int wave = tid >> 6, lane = tid & 63;
    if (lane == 0) sw[wave] = ss;
    __syncthreads();
    float tot = sw[0] + sw[1] + sw[2] + sw[3];
    float r = rsqrtf(tot / (float)DI + 1e-5f);
#pragma unroll
    for (int j = 0; j < 8; j++) {
        int d = tid + j * 256;
        yg[(size_t)tok * DI + d] = (bf16_t)(g[j] * r * nw[d]);
    }
}

extern "C" void kernel_launch(void* const* d_in, const int* in_sizes, int n_in,
                              void* d_out, int out_size, void* d_ws, size_t ws_size,
                              hipStream_t stream) {
    const float* u       = (const float*)d_in[0];
    const float* delta_t = (const float*)d_in[1];
    const float* W_in    = (const float*)d_in[2];
    const float* conv_w  = (const float*)d_in[3];
    const float* conv_b  = (const float*)d_in[4];
    const float* dt_bias = (const float*)d_in[5];
    const float* gamma   = (const float*)d_in[6];
    const float* A_log   = (const float*)d_in[7];
    const float* Dp      = (const float*)d_in[8];
    const float* norm_w  = (const float*)d_in[9];
    const float* W_out   = (const float*)d_in[10];
    float* out = (float*)d_out;

    char* p = (char*)d_ws;
    auto alloc = [&](size_t bytes) -> char* {
        char* r = p;
        p += (bytes + 255) & ~(size_t)255;
        return r;
    };
    bf16_t* zxBC    = (bf16_t*)alloc((size_t)NTOK * NPX * 2);
    bf16_t* Win_bf  = (bf16_t*)alloc((size_t)NP1 * DM * 2);
    bf16_t* Wout_bf = (bf16_t*)alloc((size_t)DM * DI * 2);
    float*  dtb     = (float*)alloc((size_t)NTOK * NH * 4);
    float*  acum    = (float*)alloc((size_t)NTOK * NH * 4);
    bf16_t* xBC_bf  = (bf16_t*)alloc((size_t)NTOK * CD * 2);
    bf16_t* Xt      = (bf16_t*)alloc((size_t)NTOK * DI * 2);
    bf16_t* poolA   = (bf16_t*)alloc((size_t)NTOK * DM * 2);
    bf16_t* Btr     = (bf16_t*)alloc((size_t)BSZ * NCH * DS * CH * 2);
    bf16_t* Sraw    = (bf16_t*)alloc((size_t)BSZ * NCH * 6 * 64 * 64 * 2);
    // d_out scratch phases (stream-ordered, each dead before next use):
    float*  dtf     = (float*)d_out;            // 1 MB
    bf16_t* states  = (bf16_t*)d_out;           // 16.8 MB
    bf16_t* yf      = (bf16_t*)d_out;           // 33.5 MB
    bf16_t* u_bf    = poolA;
    bf16_t* prevb   = poolA;
    bf16_t* yg_bf   = Xt;

    k_cvt_all<<<(CVT_U + CVT_WI + CVT_WO + 255) / 256, 256, 0, stream>>>(
        u, W_in, W_out, u_bf, Win_bf, Wout_bf);

    // main GEMM: mtiles=64, ntiles=34, 1-D grid with XCD-aware decode
    k_gemm<bf16_t><<<64 * 34, 256, 0, stream>>>(u_bf, Win_bf, zxBC, DM, NPX, 64, 34);
    k_dtgemm<<<NTOK / 128, 256, 0, stream>>>(u_bf, Win_bf + (size_t)NPX * DM, dtf);

    k_mid1<<<1024 + 9 * (NTOK / 8), 256, 0, stream>>>(dtf, delta_t, gamma, dt_bias, A_log,
                                                      dtb, acum, zxBC + DI, conv_w, conv_b, xBC_bf);
    k_mid2<<<192 + 34 * BSZ * NCH, 256, 0, stream>>>(xBC_bf, dtb, Xt, Btr, Sraw);
    k_states<<<BSZ * NCH * NH, 256, 0, stream>>>(Xt, Btr, acum, states);
    k_scan<<<BSZ * NH * 32, 256, 0, stream>>>(states, acum, prevb);
    k_chunky<<<BSZ * NCH * NH, 256, 0, stream>>>(xBC_bf, Xt, prevb, Sraw, acum, Dp, yf);
    k_gate<<<NTOK, 256, 0, stream>>>(yf, zxBC, norm_w, yg_bf);

    // out GEMM: mtiles=64, ntiles=8
    k_gemm<float><<<64 * 8, 256, 0, stream>>>(yg_bf, Wout_bf, out, DI, DM, 64, 8);
}